// Round 2
// baseline (380.543 us; speedup 1.0000x reference)
//
#include <hip/hip_runtime.h>

typedef unsigned short u16;
typedef __attribute__((ext_vector_type(8))) __bf16 bf16x8;
typedef __attribute__((ext_vector_type(8))) u16 u16x8;
typedef __attribute__((ext_vector_type(4))) float f32x4;

__device__ __forceinline__ float bf2f(u16 u){
  union { unsigned int i; float f; } v; v.i = ((unsigned int)u) << 16; return v.f;
}
__device__ __forceinline__ u16 f2bf(float f){
  union { float f; unsigned int u; } v; v.f = f;
  unsigned int u = v.u;
  u += 0x7FFFu + ((u >> 16) & 1u);
  return (u16)(u >> 16);
}

// ---------- transpose f32[R,C] -> bf16[C,R], dims multiple of 32 ----------
__global__ __launch_bounds__(256) void transpose_k(const float* __restrict__ in, u16* __restrict__ out,
                                                   int R, int C){
  __shared__ float tile[32][33];
  const int bx = blockIdx.x * 32, by = blockIdx.y * 32;
  const int tx = threadIdx.x, ty = threadIdx.y;   // block (32,8)
  #pragma unroll
  for(int i = 0; i < 32; i += 8)
    tile[ty + i][tx] = in[(size_t)(by + ty + i) * C + bx + tx];
  __syncthreads();
  #pragma unroll
  for(int i = 0; i < 32; i += 8)
    out[(size_t)(bx + ty + i) * R + by + tx] = f2bf(tile[tx][ty + i]);
}

// ---------- LayerNorm rows of 1024: f32 in -> bf16 out, one block/row ----------
__global__ __launch_bounds__(256) void ln_k(const float* __restrict__ x, const float* __restrict__ gw,
                                            const float* __restrict__ bw, u16* __restrict__ xnb){
  const int row = blockIdx.x, t = threadIdx.x;
  const float* xr = x + (size_t)row * 1024;
  float4 xv = *reinterpret_cast<const float4*>(xr + t * 4);
  float s  = xv.x + xv.y + xv.z + xv.w;
  float s2 = xv.x*xv.x + xv.y*xv.y + xv.z*xv.z + xv.w*xv.w;
  #pragma unroll
  for(int m = 1; m <= 32; m <<= 1){ s += __shfl_xor(s, m, 64); s2 += __shfl_xor(s2, m, 64); }
  __shared__ float red[8];
  const int w = t >> 6, lane = t & 63;
  if(lane == 0){ red[w] = s; red[4 + w] = s2; }
  __syncthreads();
  float S1 = red[0] + red[1] + red[2] + red[3];
  float S2 = red[4] + red[5] + red[6] + red[7];
  float mu = S1 * (1.f/1024.f);
  float var = S2 * (1.f/1024.f) - mu * mu;
  float rstd = rsqrtf(var + 1e-5f);
  float4 gv = *reinterpret_cast<const float4*>(gw + t * 4);
  float4 bv = *reinterpret_cast<const float4*>(bw + t * 4);
  ushort4 o;
  o.x = f2bf((xv.x - mu) * rstd * gv.x + bv.x);
  o.y = f2bf((xv.y - mu) * rstd * gv.y + bv.y);
  o.z = f2bf((xv.z - mu) * rstd * gv.z + bv.z);
  o.w = f2bf((xv.w - mu) * rstd * gv.w + bv.w);
  *reinterpret_cast<ushort4*>(xnb + (size_t)row * 1024 + t * 4) = o;
}

// ---------- rk0 = r @ Wr : [1024], f32 ----------
__global__ __launch_bounds__(256) void rk0_k(const float* __restrict__ r, const float* __restrict__ Wr,
                                             float* __restrict__ rk0){
  const int n = blockIdx.x * 256 + threadIdx.x;
  float acc = 0.f;
  for(int d = 0; d < 1024; ++d)
    acc += r[d] * Wr[(size_t)d * 1024 + n];
  rk0[n] = acc;
}

// ---------- c[i,b,h] = sum_d (q + rr) * rk0 ; one wave per (i*B+b) ----------
__global__ __launch_bounds__(64) void c_k(const u16* __restrict__ qkv, const float* __restrict__ rr,
                                          const float* __restrict__ rk0, float* __restrict__ cc){
  const int ib = blockIdx.x;          // i*B + b
  const int lane = threadIdx.x;       // 64 == Dh
  const u16* qrow = qkv + (size_t)ib * 3072;
  for(int h = 0; h < 16; ++h){
    float v = (bf2f(qrow[h * 64 + lane]) + rr[h * 64 + lane]) * rk0[h * 64 + lane];
    #pragma unroll
    for(int m = 32; m >= 1; m >>= 1) v += __shfl_xor(v, m, 64);
    if(lane == 0) cc[(size_t)ib * 16 + h] = v;
  }
}

// ---------- GEMM: C[M,N] = A[M,K] @ BT[N,K]^T (+ optional bf16 residual) ----------
// OT = u16 (store bf16) or float (store f32)
template<int ADD_RES, typename OT>
__global__ __launch_bounds__(256) void gemm_bt_k(const u16* __restrict__ A, const u16* __restrict__ BT,
                                                 const u16* __restrict__ res, OT* __restrict__ C,
                                                 int M, int N, int K){
  __shared__ u16 sA[128 * 40];
  __shared__ u16 sB[128 * 40];
  const int t = threadIdx.x;
  const int row0 = blockIdx.y * 128, col0 = blockIdx.x * 128;
  const int w = t >> 6, lane = t & 63, g = lane >> 4, lq = lane & 15;
  const int wr = (w >> 1) * 64, wc = (w & 1) * 64;
  f32x4 zero4 = {0.f, 0.f, 0.f, 0.f};
  f32x4 acc[4][4];
  #pragma unroll
  for(int mi = 0; mi < 4; ++mi)
    #pragma unroll
    for(int ni = 0; ni < 4; ++ni) acc[mi][ni] = zero4;

  for(int kt = 0; kt < K; kt += 32){
    #pragma unroll
    for(int p = 0; p < 2; ++p){
      const int idx = p * 2048 + t * 8;
      const int r = idx >> 5, c = idx & 31;
      *reinterpret_cast<u16x8*>(&sA[r * 40 + c]) =
          *reinterpret_cast<const u16x8*>(A + (size_t)(row0 + r) * K + kt + c);
      *reinterpret_cast<u16x8*>(&sB[r * 40 + c]) =
          *reinterpret_cast<const u16x8*>(BT + (size_t)(col0 + r) * K + kt + c);
    }
    __syncthreads();
    bf16x8 af[4];
    #pragma unroll
    for(int mi = 0; mi < 4; ++mi)
      af[mi] = *reinterpret_cast<const bf16x8*>(&sA[(wr + mi * 16 + lq) * 40 + g * 8]);
    #pragma unroll
    for(int ni = 0; ni < 4; ++ni){
      bf16x8 bfr = *reinterpret_cast<const bf16x8*>(&sB[(wc + ni * 16 + lq) * 40 + g * 8]);
      #pragma unroll
      for(int mi = 0; mi < 4; ++mi)
        acc[mi][ni] = __builtin_amdgcn_mfma_f32_16x16x32_bf16(af[mi], bfr, acc[mi][ni], 0, 0, 0);
    }
    __syncthreads();
  }
  #pragma unroll
  for(int mi = 0; mi < 4; ++mi)
    #pragma unroll
    for(int ni = 0; ni < 4; ++ni)
      #pragma unroll
      for(int rg = 0; rg < 4; ++rg){
        const int row = row0 + wr + mi * 16 + g * 4 + rg;
        const int col = col0 + wc + ni * 16 + lq;
        float v = acc[mi][ni][rg];
        if(ADD_RES) v += bf2f(res[(size_t)row * N + col]);
        if constexpr (sizeof(OT) == 2) C[(size_t)row * N + col] = f2bf(v);
        else                           C[(size_t)row * N + col] = v;
      }
}

// ---------- flash attention with collapsed BD term ----------
// BD[i,j] after rel_shift: ci (j<=i), 0 (j==i+1), cp=c[i+1] (j>=i+2)
// grid: (S/64, B*H); block 256 = 4 waves, wave w owns q-rows [i0+16w, i0+16w+16)
__global__ __launch_bounds__(256) void attn_k(const u16* __restrict__ qkv, const float* __restrict__ rw,
                                              const float* __restrict__ cc, u16* __restrict__ av){
  constexpr int S = 2048, B = 2;
  __shared__ u16 qh[64 * 72];       // (q + rw), rows=qrow, cols=d
  __shared__ u16 ks[64 * 72];       // K tile, rows=key j, cols=d
  __shared__ u16 vs[64 * 72];       // V^T tile, rows=d, cols=key j
  __shared__ u16 ps[4][16 * 72];    // per-wave P round-trip (C-layout -> A-layout)
  const int t = threadIdx.x;
  const int i0 = blockIdx.x * 64;
  const int b = blockIdx.y >> 4, h = blockIdx.y & 15;
  const int w = t >> 6, lane = t & 63, g = lane >> 4, lq = lane & 15;

  { // stage q + rw (each thread writes rows of its own wave)
    const int r = t >> 2, dbase = (t & 3) * 16;
    const u16* qp = qkv + ((size_t)(i0 + r) * B + b) * 3072 + h * 64 + dbase;
    #pragma unroll
    for(int e = 0; e < 16; ++e)
      qh[r * 72 + dbase + e] = f2bf(bf2f(qp[e]) + rw[h * 64 + dbase + e]);
  }
  float ci[4], cp[4];
  #pragma unroll
  for(int rg = 0; rg < 4; ++rg){
    const int i = i0 + w * 16 + g * 4 + rg;
    ci[rg] = cc[((size_t)i * B + b) * 16 + h];
    cp[rg] = (i + 1 < S) ? cc[((size_t)(i + 1) * B + b) * 16 + h] : 0.0f;
  }
  float mrow[4] = {-1e30f, -1e30f, -1e30f, -1e30f};
  float lrow[4] = {0.f, 0.f, 0.f, 0.f};
  f32x4 zero4 = {0.f, 0.f, 0.f, 0.f};
  f32x4 acc[4];
  #pragma unroll
  for(int ni = 0; ni < 4; ++ni) acc[ni] = zero4;
  const float scale = 0.125f;

  for(int j0 = 0; j0 < S; j0 += 64){
    { // stage K tile (direct) and V tile (transposed)
      const int jr = t >> 2, dbase = (t & 3) * 16;
      const u16* kp = qkv + ((size_t)(j0 + jr) * B + b) * 3072 + 1024 + h * 64 + dbase;
      *reinterpret_cast<u16x8*>(&ks[jr * 72 + dbase])     = *reinterpret_cast<const u16x8*>(kp);
      *reinterpret_cast<u16x8*>(&ks[jr * 72 + dbase + 8]) = *reinterpret_cast<const u16x8*>(kp + 8);
      const u16* vp = qkv + ((size_t)(j0 + jr) * B + b) * 3072 + 2048 + h * 64 + dbase;
      #pragma unroll
      for(int e = 0; e < 16; ++e) vs[(dbase + e) * 72 + jr] = vp[e];
    }
    __syncthreads();

    // QK^T : Sc[16 x 64] per wave
    bf16x8 aq0 = *reinterpret_cast<const bf16x8*>(&qh[(w * 16 + lq) * 72 + g * 8]);
    bf16x8 aq1 = *reinterpret_cast<const bf16x8*>(&qh[(w * 16 + lq) * 72 + 32 + g * 8]);
    float sc[4][4];
    #pragma unroll
    for(int jt = 0; jt < 4; ++jt){
      f32x4 s4 = zero4;
      bf16x8 b0 = *reinterpret_cast<const bf16x8*>(&ks[(jt * 16 + lq) * 72 + g * 8]);
      s4 = __builtin_amdgcn_mfma_f32_16x16x32_bf16(aq0, b0, s4, 0, 0, 0);
      bf16x8 b1 = *reinterpret_cast<const bf16x8*>(&ks[(jt * 16 + lq) * 72 + 32 + g * 8]);
      s4 = __builtin_amdgcn_mfma_f32_16x16x32_bf16(aq1, b1, s4, 0, 0, 0);
      #pragma unroll
      for(int rg = 0; rg < 4; ++rg) sc[jt][rg] = s4[rg];
    }
    // scores = (AC + BD) * scale
    float mnew[4];
    #pragma unroll
    for(int rg = 0; rg < 4; ++rg) mnew[rg] = mrow[rg];
    #pragma unroll
    for(int jt = 0; jt < 4; ++jt)
      #pragma unroll
      for(int rg = 0; rg < 4; ++rg){
        const int i = i0 + w * 16 + g * 4 + rg;
        const int j = j0 + jt * 16 + lq;
        const float bd = (j <= i) ? ci[rg] : ((j == i + 1) ? 0.0f : cp[rg]);
        const float s = (sc[jt][rg] + bd) * scale;
        sc[jt][rg] = s;
        mnew[rg] = fmaxf(mnew[rg], s);
      }
    #pragma unroll
    for(int rg = 0; rg < 4; ++rg){
      #pragma unroll
      for(int m = 1; m <= 8; m <<= 1)
        mnew[rg] = fmaxf(mnew[rg], __shfl_xor(mnew[rg], m, 64));
    }
    float alpha[4], rs[4];
    #pragma unroll
    for(int rg = 0; rg < 4; ++rg){
      alpha[rg] = expf(mrow[rg] - mnew[rg]);
      mrow[rg] = mnew[rg];
      rs[rg] = 0.f;
    }
    #pragma unroll
    for(int jt = 0; jt < 4; ++jt)
      #pragma unroll
      for(int rg = 0; rg < 4; ++rg){
        const float p = expf(sc[jt][rg] - mnew[rg]);
        sc[jt][rg] = p;
        rs[rg] += p;
      }
    #pragma unroll
    for(int rg = 0; rg < 4; ++rg){
      #pragma unroll
      for(int m = 1; m <= 8; m <<= 1) rs[rg] += __shfl_xor(rs[rg], m, 64);
      lrow[rg] = lrow[rg] * alpha[rg] + rs[rg];
    }
    #pragma unroll
    for(int ni = 0; ni < 4; ++ni)
      #pragma unroll
      for(int rg = 0; rg < 4; ++rg) acc[ni][rg] *= alpha[rg];
    // P: C-layout -> LDS -> A-layout (barrier makes ordering airtight)
    #pragma unroll
    for(int jt = 0; jt < 4; ++jt)
      #pragma unroll
      for(int rg = 0; rg < 4; ++rg)
        ps[w][(g * 4 + rg) * 72 + jt * 16 + lq] = f2bf(sc[jt][rg]);
    __syncthreads();
    bf16x8 ap0 = *reinterpret_cast<const bf16x8*>(&ps[w][lq * 72 + g * 8]);
    bf16x8 ap1 = *reinterpret_cast<const bf16x8*>(&ps[w][lq * 72 + 32 + g * 8]);
    #pragma unroll
    for(int ni = 0; ni < 4; ++ni){
      bf16x8 bv0 = *reinterpret_cast<const bf16x8*>(&vs[(ni * 16 + lq) * 72 + g * 8]);
      acc[ni] = __builtin_amdgcn_mfma_f32_16x16x32_bf16(ap0, bv0, acc[ni], 0, 0, 0);
      bf16x8 bv1 = *reinterpret_cast<const bf16x8*>(&vs[(ni * 16 + lq) * 72 + 32 + g * 8]);
      acc[ni] = __builtin_amdgcn_mfma_f32_16x16x32_bf16(ap1, bv1, acc[ni], 0, 0, 0);
    }
    __syncthreads();
  }
  #pragma unroll
  for(int ni = 0; ni < 4; ++ni)
    #pragma unroll
    for(int rg = 0; rg < 4; ++rg){
      const int i = i0 + w * 16 + g * 4 + rg;
      const int d = ni * 16 + lq;
      av[((size_t)i * B + b) * 1024 + h * 64 + d] = f2bf(acc[ni][rg] / lrow[rg]);
    }
}

extern "C" void kernel_launch(void* const* d_in, const int* in_sizes, int n_in,
                              void* d_out, int out_size, void* d_ws, size_t ws_size,
                              hipStream_t stream){
  (void)in_sizes; (void)n_in; (void)out_size; (void)ws_size;
  const float* x    = (const float*)d_in[0];
  const float* r    = (const float*)d_in[1];
  const float* rw   = (const float*)d_in[2];
  const float* rr   = (const float*)d_in[3];
  const float* ln_g = (const float*)d_in[4];
  const float* ln_b = (const float*)d_in[5];
  const float* Wqkv = (const float*)d_in[6];
  const float* Wr   = (const float*)d_in[7];
  const float* Wo   = (const float*)d_in[8];
  char* ws = (char*)d_ws;
  u16*   xnb   = (u16*)(ws + 0);                    //  8 MB  bf16 [4096,1024]
  u16*   qkv   = (u16*)(ws + 8388608);              // 24 MB  bf16 [4096,3072]
  u16*   av    = (u16*)(ws + 33554432);             //  8 MB  bf16 [4096,1024]
  u16*   wqkvT = (u16*)(ws + 41943040);             //  6 MB  bf16 [3072,1024]
  u16*   woT   = (u16*)(ws + 48234496);             //  2 MB  bf16 [1024,1024]
  float* rk0   = (float*)(ws + 50331648);           //  4 KB  f32 [1024]
  float* cc    = (float*)(ws + 50335744);           // 256 KB f32 [4096,16]
  float* out   = (float*)d_out;

  transpose_k<<<dim3(96, 32), dim3(32, 8), 0, stream>>>(Wqkv, wqkvT, 1024, 3072);
  transpose_k<<<dim3(32, 32), dim3(32, 8), 0, stream>>>(Wo, woT, 1024, 1024);
  ln_k<<<4096, 256, 0, stream>>>(x, ln_g, ln_b, xnb);
  rk0_k<<<4, 256, 0, stream>>>(r, Wr, rk0);
  gemm_bt_k<0, u16><<<dim3(24, 32), 256, 0, stream>>>(xnb, wqkvT, nullptr, qkv, 4096, 3072, 1024);
  c_k<<<4096, 64, 0, stream>>>(qkv, rr, rk0, cc);
  attn_k<<<dim3(32, 32), 256, 0, stream>>>(qkv, rw, cc, av);
  gemm_bt_k<1, float><<<dim3(8, 32), 256, 0, stream>>>(av, woT, xnb, out, 4096, 1024, 1024);
}

// Round 3
// 264.028 us; speedup vs baseline: 1.4413x; 1.4413x over previous
//
#include <hip/hip_runtime.h>

typedef unsigned short u16;
typedef __attribute__((ext_vector_type(8))) __bf16 bf16x8;
typedef __attribute__((ext_vector_type(8))) u16 u16x8;
typedef __attribute__((ext_vector_type(4))) float f32x4;

__device__ __forceinline__ float bf2f(u16 u){
  union { unsigned int i; float f; } v; v.i = ((unsigned int)u) << 16; return v.f;
}
__device__ __forceinline__ u16 f2bf(float f){
  union { float f; unsigned int u; } v; v.f = f;
  unsigned int u = v.u;
  u += 0x7FFFu + ((u >> 16) & 1u);
  return (u16)(u >> 16);
}
// async global->LDS, 16B per lane; LDS dest = wave-uniform base + lane*16
__device__ __forceinline__ void gld_lds16(const u16* g, u16* l){
  __builtin_amdgcn_global_load_lds((const __attribute__((address_space(1))) unsigned int*)g,
                                   (__attribute__((address_space(3))) unsigned int*)l, 16, 0, 0);
}

// ---------- transpose f32[R,C] -> bf16[C,R], dims multiple of 32 ----------
__global__ __launch_bounds__(256) void transpose_k(const float* __restrict__ in, u16* __restrict__ out,
                                                   int R, int C){
  __shared__ float tile[32][33];
  const int bx = blockIdx.x * 32, by = blockIdx.y * 32;
  const int tx = threadIdx.x, ty = threadIdx.y;   // block (32,8)
  #pragma unroll
  for(int i = 0; i < 32; i += 8)
    tile[ty + i][tx] = in[(size_t)(by + ty + i) * C + bx + tx];
  __syncthreads();
  #pragma unroll
  for(int i = 0; i < 32; i += 8)
    out[(size_t)(bx + ty + i) * R + by + tx] = f2bf(tile[tx][ty + i]);
}

// ---------- LayerNorm rows of 1024: f32 in -> bf16 out ----------
__global__ __launch_bounds__(256) void ln_k(const float* __restrict__ x, const float* __restrict__ gw,
                                            const float* __restrict__ bw, u16* __restrict__ xnb){
  const int row = blockIdx.x, t = threadIdx.x;
  const float* xr = x + (size_t)row * 1024;
  float4 xv = *reinterpret_cast<const float4*>(xr + t * 4);
  float s  = xv.x + xv.y + xv.z + xv.w;
  float s2 = xv.x*xv.x + xv.y*xv.y + xv.z*xv.z + xv.w*xv.w;
  #pragma unroll
  for(int m = 1; m <= 32; m <<= 1){ s += __shfl_xor(s, m, 64); s2 += __shfl_xor(s2, m, 64); }
  __shared__ float red[8];
  const int w = t >> 6, lane = t & 63;
  if(lane == 0){ red[w] = s; red[4 + w] = s2; }
  __syncthreads();
  float S1 = red[0] + red[1] + red[2] + red[3];
  float S2 = red[4] + red[5] + red[6] + red[7];
  float mu = S1 * (1.f/1024.f);
  float var = S2 * (1.f/1024.f) - mu * mu;
  float rstd = rsqrtf(var + 1e-5f);
  float4 gv = *reinterpret_cast<const float4*>(gw + t * 4);
  float4 bv = *reinterpret_cast<const float4*>(bw + t * 4);
  ushort4 o;
  o.x = f2bf((xv.x - mu) * rstd * gv.x + bv.x);
  o.y = f2bf((xv.y - mu) * rstd * gv.y + bv.y);
  o.z = f2bf((xv.z - mu) * rstd * gv.z + bv.z);
  o.w = f2bf((xv.w - mu) * rstd * gv.w + bv.w);
  *reinterpret_cast<ushort4*>(xnb + (size_t)row * 1024 + t * 4) = o;
}

// ---------- rk0 = r @ Wr : [1024], split over d with atomics (rk0 pre-zeroed) ----------
__global__ __launch_bounds__(256) void rk0_k(const float* __restrict__ r, const float* __restrict__ Wr,
                                             float* __restrict__ rk0){
  const int n = blockIdx.x * 256 + threadIdx.x;
  const int d0 = blockIdx.y * 128;
  float acc = 0.f;
  for(int d = d0; d < d0 + 128; ++d)
    acc += r[d] * Wr[(size_t)d * 1024 + n];
  atomicAdd(&rk0[n], acc);
}

// ---------- c[ib][h] = sum_d (q + rr) * rk0 ; one wave per ib ----------
__global__ __launch_bounds__(256) void c_k(const u16* __restrict__ qk, const float* __restrict__ rr,
                                           const float* __restrict__ rk0, float* __restrict__ cc){
  const int w = threadIdx.x >> 6, lane = threadIdx.x & 63;
  const int ib = blockIdx.x * 4 + w;
  const u16* qp = qk + (size_t)ib * 2048 + lane * 16;
  u16x8 q0 = *reinterpret_cast<const u16x8*>(qp);
  u16x8 q1 = *reinterpret_cast<const u16x8*>(qp + 8);
  const float* rrp = rr + lane * 16;
  const float* rkp = rk0 + lane * 16;
  float s = 0.f;
  #pragma unroll
  for(int e = 0; e < 8; ++e){
    s += (bf2f(q0[e]) + rrp[e]) * rkp[e];
    s += (bf2f(q1[e]) + rrp[8 + e]) * rkp[8 + e];
  }
  s += __shfl_xor(s, 1, 64);
  s += __shfl_xor(s, 2, 64);
  if((lane & 3) == 0) cc[(size_t)ib * 16 + (lane >> 2)] = s;
}

// ---------- GEMM: C[M,N] = A[M,K] @ BT[N,K]^T ----------
// MODE 1: f32 out + bf16 residual ; MODE 2: split: col<2048 -> bf16 qk (stride 2048),
//         col>=2048 -> vT[(b*16+h)*64+d][i] transposed bf16 store
template<int MODE>
__global__ __launch_bounds__(256) void gemm_bt_k(const u16* __restrict__ A, const u16* __restrict__ BT,
                                                 const u16* __restrict__ res, u16* __restrict__ Cb,
                                                 float* __restrict__ Cf, u16* __restrict__ vT,
                                                 int M, int N, int K){
  __shared__ u16 sA[128 * 32];
  __shared__ u16 sB[128 * 32];
  const int t = threadIdx.x;
  const int row0 = blockIdx.y * 128, col0 = blockIdx.x * 128;
  const int w = t >> 6, lane = t & 63, g = lane >> 4, lq = lane & 15;
  const int wr = (w >> 1) * 64, wc = (w & 1) * 64;
  const int s0 = t, s1 = t + 256;       // 16B staging slots
  f32x4 zero4 = {0.f, 0.f, 0.f, 0.f};
  f32x4 acc[4][4];
  #pragma unroll
  for(int mi = 0; mi < 4; ++mi)
    #pragma unroll
    for(int ni = 0; ni < 4; ++ni) acc[mi][ni] = zero4;

  for(int kt = 0; kt < K; kt += 32){
    gld_lds16(A  + (size_t)(row0 + (s0 >> 2)) * K + kt + (s0 & 3) * 8, &sA[w * 512]);
    gld_lds16(A  + (size_t)(row0 + (s1 >> 2)) * K + kt + (s1 & 3) * 8, &sA[2048 + w * 512]);
    gld_lds16(BT + (size_t)(col0 + (s0 >> 2)) * K + kt + (s0 & 3) * 8, &sB[w * 512]);
    gld_lds16(BT + (size_t)(col0 + (s1 >> 2)) * K + kt + (s1 & 3) * 8, &sB[2048 + w * 512]);
    __syncthreads();
    bf16x8 af[4];
    #pragma unroll
    for(int mi = 0; mi < 4; ++mi)
      af[mi] = *reinterpret_cast<const bf16x8*>(&sA[(wr + mi * 16 + lq) * 32 + g * 8]);
    #pragma unroll
    for(int ni = 0; ni < 4; ++ni){
      bf16x8 bfr = *reinterpret_cast<const bf16x8*>(&sB[(wc + ni * 16 + lq) * 32 + g * 8]);
      #pragma unroll
      for(int mi = 0; mi < 4; ++mi)
        acc[mi][ni] = __builtin_amdgcn_mfma_f32_16x16x32_bf16(af[mi], bfr, acc[mi][ni], 0, 0, 0);
    }
    __syncthreads();
  }
  #pragma unroll
  for(int mi = 0; mi < 4; ++mi)
    #pragma unroll
    for(int ni = 0; ni < 4; ++ni)
      #pragma unroll
      for(int rg = 0; rg < 4; ++rg){
        const int row = row0 + wr + mi * 16 + g * 4 + rg;
        const int col = col0 + wc + ni * 16 + lq;
        float v = acc[mi][ni][rg];
        if(MODE == 1){
          v += bf2f(res[(size_t)row * N + col]);
          Cf[(size_t)row * N + col] = v;
        } else {
          if(col < 2048){
            Cb[(size_t)row * 2048 + col] = f2bf(v);
          } else {
            const int b = row & 1, i = row >> 1, h = (col - 2048) >> 6, d = col & 63;
            vT[((size_t)((b << 4) + h) * 64 + d) * 2048 + i] = f2bf(v);
          }
        }
      }
}

// ---------- flash attention, collapsed BD, no-max softmax (scores bounded), deferred row-sum ----------
// grid: (S/64, B*H); block 256 = 4 waves, wave w owns q-rows [i0+16w, i0+16w+16)
__global__ __launch_bounds__(256) void attn_k(const u16* __restrict__ qk, const u16* __restrict__ vT,
                                              const float* __restrict__ rw, const float* __restrict__ cc,
                                              u16* __restrict__ av){
  constexpr int S = 2048;
  __shared__ u16 ks[2][64 * 72];    // K tile: rows=key j, cols=d
  __shared__ u16 vs[2][64 * 72];    // V^T tile: rows=d, cols=key j
  __shared__ u16 ps[4][16 * 72];    // per-wave P round-trip (C-layout -> A-layout)
  const int t = threadIdx.x;
  const int i0 = blockIdx.x * 64;
  const int bh = blockIdx.y;                    // b*16 + h
  const int b = bh >> 4, h = bh & 15;
  const int w = t >> 6, lane = t & 63, g = lane >> 4, lq = lane & 15;
  const float scale = 0.125f;

  // Q A-fragments in registers (loop-invariant): aq = (q + rw) * scale
  bf16x8 aq0, aq1;
  {
    const int irow = (i0 + w * 16 + lq) * 2 + b;
    const u16* qp = qk + (size_t)irow * 2048 + h * 64;
    u16x8 q0 = *reinterpret_cast<const u16x8*>(qp + g * 8);
    u16x8 q1 = *reinterpret_cast<const u16x8*>(qp + 32 + g * 8);
    const float* rwp = rw + h * 64 + g * 8;
    u16x8 a0, a1;
    #pragma unroll
    for(int e = 0; e < 8; ++e){
      a0[e] = f2bf((bf2f(q0[e]) + rwp[e]) * scale);
      a1[e] = f2bf((bf2f(q1[e]) + rwp[32 + e]) * scale);
    }
    aq0 = *reinterpret_cast<bf16x8*>(&a0);
    aq1 = *reinterpret_cast<bf16x8*>(&a1);
  }
  // BD term (pre-scaled): ci for j<=i, 0 for j==i+1, cp for j>=i+2
  float ci[4], cp[4];
  #pragma unroll
  for(int rg = 0; rg < 4; ++rg){
    const int i = i0 + w * 16 + g * 4 + rg;
    ci[rg] = cc[(size_t)(i * 2 + b) * 16 + h] * scale;
    cp[rg] = (i + 1 < S) ? cc[(size_t)((i + 1) * 2 + b) * 16 + h] * scale : 0.0f;
  }
  float rsum[4] = {0.f, 0.f, 0.f, 0.f};
  f32x4 zero4 = {0.f, 0.f, 0.f, 0.f};
  f32x4 acc[4];
  #pragma unroll
  for(int ni = 0; ni < 4; ++ni) acc[ni] = zero4;

  const int jr = t >> 2, c0 = (t & 3) * 16;     // staging: row, u16 col offset
  // prologue: stage tile 0 into buf 0
  {
    const u16* kp = qk + (size_t)(jr * 2 + b) * 2048 + 1024 + h * 64 + c0;
    *reinterpret_cast<u16x8*>(&ks[0][jr * 72 + c0])     = *reinterpret_cast<const u16x8*>(kp);
    *reinterpret_cast<u16x8*>(&ks[0][jr * 72 + c0 + 8]) = *reinterpret_cast<const u16x8*>(kp + 8);
    const u16* vp = vT + ((size_t)bh * 64 + jr) * 2048 + c0;
    *reinterpret_cast<u16x8*>(&vs[0][jr * 72 + c0])     = *reinterpret_cast<const u16x8*>(vp);
    *reinterpret_cast<u16x8*>(&vs[0][jr * 72 + c0 + 8]) = *reinterpret_cast<const u16x8*>(vp + 8);
  }
  __syncthreads();

  for(int n = 0; n < 32; ++n){
    const int p = n & 1;
    // issue next tile's global loads into registers (write to LDS at end of body)
    u16x8 k0, k1, v0, v1;
    const bool pre = (n + 1 < 32);
    if(pre){
      const int j0n = (n + 1) * 64;
      const u16* kp = qk + (size_t)((j0n + jr) * 2 + b) * 2048 + 1024 + h * 64 + c0;
      k0 = *reinterpret_cast<const u16x8*>(kp);
      k1 = *reinterpret_cast<const u16x8*>(kp + 8);
      const u16* vp = vT + ((size_t)bh * 64 + jr) * 2048 + j0n + c0;
      v0 = *reinterpret_cast<const u16x8*>(vp);
      v1 = *reinterpret_cast<const u16x8*>(vp + 8);
    }
    // QK^T -> scores -> p -> ps (A-layout via per-wave LDS)
    const int j0 = n * 64;
    #pragma unroll
    for(int jt = 0; jt < 4; ++jt){
      f32x4 s4 = zero4;
      bf16x8 b0 = *reinterpret_cast<const bf16x8*>(&ks[p][(jt * 16 + lq) * 72 + g * 8]);
      s4 = __builtin_amdgcn_mfma_f32_16x16x32_bf16(aq0, b0, s4, 0, 0, 0);
      bf16x8 b1 = *reinterpret_cast<const bf16x8*>(&ks[p][(jt * 16 + lq) * 72 + 32 + g * 8]);
      s4 = __builtin_amdgcn_mfma_f32_16x16x32_bf16(aq1, b1, s4, 0, 0, 0);
      const int j = j0 + jt * 16 + lq;
      #pragma unroll
      for(int rg = 0; rg < 4; ++rg){
        const int i = i0 + w * 16 + g * 4 + rg;
        const float t1 = (j <= i) ? ci[rg] : cp[rg];
        const float bd = (j == i + 1) ? 0.0f : t1;
        const float pv = __expf(s4[rg] + bd);     // no max-subtraction: scores bounded
        rsum[rg] += pv;
        ps[w][(g * 4 + rg) * 72 + jt * 16 + lq] = f2bf(pv);
      }
    }
    __asm__ __volatile__("s_waitcnt lgkmcnt(0)" ::: "memory");  // per-wave LDS RAW
    bf16x8 ap0 = *reinterpret_cast<const bf16x8*>(&ps[w][lq * 72 + g * 8]);
    bf16x8 ap1 = *reinterpret_cast<const bf16x8*>(&ps[w][lq * 72 + 32 + g * 8]);
    #pragma unroll
    for(int ni = 0; ni < 4; ++ni){
      bf16x8 bv0 = *reinterpret_cast<const bf16x8*>(&vs[p][(ni * 16 + lq) * 72 + g * 8]);
      acc[ni] = __builtin_amdgcn_mfma_f32_16x16x32_bf16(ap0, bv0, acc[ni], 0, 0, 0);
      bf16x8 bv1 = *reinterpret_cast<const bf16x8*>(&vs[p][(ni * 16 + lq) * 72 + 32 + g * 8]);
      acc[ni] = __builtin_amdgcn_mfma_f32_16x16x32_bf16(ap1, bv1, acc[ni], 0, 0, 0);
    }
    // write prefetched tile into other buffer
    if(pre){
      const int q2 = p ^ 1;
      *reinterpret_cast<u16x8*>(&ks[q2][jr * 72 + c0])     = k0;
      *reinterpret_cast<u16x8*>(&ks[q2][jr * 72 + c0 + 8]) = k1;
      *reinterpret_cast<u16x8*>(&vs[q2][jr * 72 + c0])     = v0;
      *reinterpret_cast<u16x8*>(&vs[q2][jr * 72 + c0 + 8]) = v1;
    }
    __syncthreads();
  }
  // deferred row-sum reduction (over lq within 16-lane group)
  #pragma unroll
  for(int rg = 0; rg < 4; ++rg){
    #pragma unroll
    for(int m = 1; m <= 8; m <<= 1) rsum[rg] += __shfl_xor(rsum[rg], m, 64);
    rsum[rg] = 1.0f / rsum[rg];
  }
  #pragma unroll
  for(int ni = 0; ni < 4; ++ni)
    #pragma unroll
    for(int rg = 0; rg < 4; ++rg){
      const int i = i0 + w * 16 + g * 4 + rg;
      const int d = ni * 16 + lq;
      av[(size_t)(i * 2 + b) * 1024 + h * 64 + d] = f2bf(acc[ni][rg] * rsum[rg]);
    }
}

extern "C" void kernel_launch(void* const* d_in, const int* in_sizes, int n_in,
                              void* d_out, int out_size, void* d_ws, size_t ws_size,
                              hipStream_t stream){
  (void)in_sizes; (void)n_in; (void)out_size; (void)ws_size;
  const float* x    = (const float*)d_in[0];
  const float* r    = (const float*)d_in[1];
  const float* rw   = (const float*)d_in[2];
  const float* rr   = (const float*)d_in[3];
  const float* ln_g = (const float*)d_in[4];
  const float* ln_b = (const float*)d_in[5];
  const float* Wqkv = (const float*)d_in[6];
  const float* Wr   = (const float*)d_in[7];
  const float* Wo   = (const float*)d_in[8];
  char* ws = (char*)d_ws;
  u16*   xnb   = (u16*)(ws + 0);                    //  8 MB bf16 [4096,1024]
  u16*   qk    = (u16*)(ws + 8388608);              // 16 MB bf16 [4096,2048] (q | k)
  u16*   av    = (u16*)(ws + 25165824);             //  8 MB bf16 [4096,1024]
  u16*   woT   = (u16*)(ws + 33554432);             //  2 MB bf16 [1024,1024]
  u16*   wqkvT = (u16*)(ws + 35651584);             //  6 MB bf16 [3072,1024]
  u16*   vT    = (u16*)(ws + 41943040);             //  8 MB bf16 [32,64,2048]
  float* rk0   = (float*)(ws + 50331648);           //  4 KB f32 [1024]
  float* cc    = (float*)(ws + 50335744);           // 256 KB f32 [4096,16]
  float* out   = (float*)d_out;

  transpose_k<<<dim3(96, 32), dim3(32, 8), 0, stream>>>(Wqkv, wqkvT, 1024, 3072);
  transpose_k<<<dim3(32, 32), dim3(32, 8), 0, stream>>>(Wo, woT, 1024, 1024);
  ln_k<<<4096, 256, 0, stream>>>(x, ln_g, ln_b, xnb);
  hipMemsetAsync(rk0, 0, 4096, stream);
  rk0_k<<<dim3(4, 8), 256, 0, stream>>>(r, Wr, rk0);
  gemm_bt_k<2><<<dim3(24, 32), 256, 0, stream>>>(xnb, wqkvT, nullptr, qk, nullptr, vT, 4096, 3072, 1024);
  c_k<<<1024, 256, 0, stream>>>(qk, rr, rk0, cc);
  attn_k<<<dim3(32, 32), 256, 0, stream>>>(qk, vT, rw, cc, av);
  gemm_bt_k<1><<<dim3(8, 32), 256, 0, stream>>>(av, woT, xnb, nullptr, out, nullptr, 4096, 1024, 1024);
}

// Round 4
// 253.890 us; speedup vs baseline: 1.4988x; 1.0399x over previous
//
#include <hip/hip_runtime.h>

typedef unsigned short u16;
typedef __attribute__((ext_vector_type(8))) __bf16 bf16x8;
typedef __attribute__((ext_vector_type(8))) u16 u16x8;
typedef __attribute__((ext_vector_type(4))) float f32x4;

__device__ __forceinline__ float bf2f(u16 u){
  union { unsigned int i; float f; } v; v.i = ((unsigned int)u) << 16; return v.f;
}
__device__ __forceinline__ u16 f2bf(float f){
  union { float f; unsigned int u; } v; v.f = f;
  unsigned int u = v.u;
  u += 0x7FFFu + ((u >> 16) & 1u);
  return (u16)(u >> 16);
}
__device__ __forceinline__ unsigned fbits(float f){
  union { float f; unsigned u; } v; v.f = f; return v.u;
}
// async global->LDS, 16B per lane; LDS dest = wave-uniform base + lane*16
__device__ __forceinline__ void gld_lds16(const u16* g, u16* l){
  __builtin_amdgcn_global_load_lds((const __attribute__((address_space(1))) unsigned int*)g,
                                   (__attribute__((address_space(3))) unsigned int*)l, 16, 0, 0);
}

// ---------- transpose f32[R,C] -> bf16[C,R], dims multiple of 32 ----------
__global__ __launch_bounds__(256) void transpose_k(const float* __restrict__ in, u16* __restrict__ out,
                                                   int R, int C){
  __shared__ float tile[32][33];
  const int bx = blockIdx.x * 32, by = blockIdx.y * 32;
  const int tx = threadIdx.x, ty = threadIdx.y;   // block (32,8)
  #pragma unroll
  for(int i = 0; i < 32; i += 8)
    tile[ty + i][tx] = in[(size_t)(by + ty + i) * C + bx + tx];
  __syncthreads();
  #pragma unroll
  for(int i = 0; i < 32; i += 8)
    out[(size_t)(bx + ty + i) * R + by + tx] = f2bf(tile[tx][ty + i]);
}

// ---------- LayerNorm rows of 1024: f32 in -> bf16 out ----------
__global__ __launch_bounds__(256) void ln_k(const float* __restrict__ x, const float* __restrict__ gw,
                                            const float* __restrict__ bw, u16* __restrict__ xnb){
  const int row = blockIdx.x, t = threadIdx.x;
  const float* xr = x + (size_t)row * 1024;
  float4 xv = *reinterpret_cast<const float4*>(xr + t * 4);
  float s  = xv.x + xv.y + xv.z + xv.w;
  float s2 = xv.x*xv.x + xv.y*xv.y + xv.z*xv.z + xv.w*xv.w;
  #pragma unroll
  for(int m = 1; m <= 32; m <<= 1){ s += __shfl_xor(s, m, 64); s2 += __shfl_xor(s2, m, 64); }
  __shared__ float red[8];
  const int w = t >> 6, lane = t & 63;
  if(lane == 0){ red[w] = s; red[4 + w] = s2; }
  __syncthreads();
  float S1 = red[0] + red[1] + red[2] + red[3];
  float S2 = red[4] + red[5] + red[6] + red[7];
  float mu = S1 * (1.f/1024.f);
  float var = S2 * (1.f/1024.f) - mu * mu;
  float rstd = rsqrtf(var + 1e-5f);
  float4 gv = *reinterpret_cast<const float4*>(gw + t * 4);
  float4 bv = *reinterpret_cast<const float4*>(bw + t * 4);
  ushort4 o;
  o.x = f2bf((xv.x - mu) * rstd * gv.x + bv.x);
  o.y = f2bf((xv.y - mu) * rstd * gv.y + bv.y);
  o.z = f2bf((xv.z - mu) * rstd * gv.z + bv.z);
  o.w = f2bf((xv.w - mu) * rstd * gv.w + bv.w);
  *reinterpret_cast<ushort4*>(xnb + (size_t)row * 1024 + t * 4) = o;
}

// ---------- rk0 = r @ Wr : [1024], split over d with atomics (rk0 pre-zeroed) ----------
__global__ __launch_bounds__(256) void rk0_k(const float* __restrict__ r, const float* __restrict__ Wr,
                                             float* __restrict__ rk0){
  const int n = blockIdx.x * 256 + threadIdx.x;
  const int d0 = blockIdx.y * 128;
  float acc = 0.f;
  for(int d = d0; d < d0 + 128; ++d)
    acc += r[d] * Wr[(size_t)d * 1024 + n];
  atomicAdd(&rk0[n], acc);
}

// ---------- c[ib][h] = sum_d (q + rr) * rk0 ; one wave per ib ----------
__global__ __launch_bounds__(256) void c_k(const u16* __restrict__ qk, const float* __restrict__ rr,
                                           const float* __restrict__ rk0, float* __restrict__ cc){
  const int w = threadIdx.x >> 6, lane = threadIdx.x & 63;
  const int ib = blockIdx.x * 4 + w;
  const u16* qp = qk + (size_t)ib * 2048 + lane * 16;
  u16x8 q0 = *reinterpret_cast<const u16x8*>(qp);
  u16x8 q1 = *reinterpret_cast<const u16x8*>(qp + 8);
  const float* rrp = rr + lane * 16;
  const float* rkp = rk0 + lane * 16;
  float s = 0.f;
  #pragma unroll
  for(int e = 0; e < 8; ++e){
    s += (bf2f(q0[e]) + rrp[e]) * rkp[e];
    s += (bf2f(q1[e]) + rrp[8 + e]) * rkp[8 + e];
  }
  s += __shfl_xor(s, 1, 64);
  s += __shfl_xor(s, 2, 64);
  if((lane & 3) == 0) cc[(size_t)ib * 16 + (lane >> 2)] = s;
}

// ---------- V transpose: v_nat[i*2+b][h*64+d] -> vT[(b*16+h)*64+d][i] ----------
// grid (16 [i tiles of 128], 32 [col tiles of 32], 2 [b]); block 256
__global__ __launch_bounds__(256) void vtrans_k(const u16* __restrict__ vnat, u16* __restrict__ vT){
  __shared__ u16 tl[128][40];
  const int t = threadIdx.x;
  const int i0 = blockIdx.x * 128, c0 = blockIdx.y * 32, b = blockIdx.z;
  {
    const int ii = t & 127, cs = (t >> 7) * 16;
    const u16* p = vnat + (size_t)((i0 + ii) * 2 + b) * 1024 + c0 + cs;
    *reinterpret_cast<u16x8*>(&tl[ii][cs])     = *reinterpret_cast<const u16x8*>(p);
    *reinterpret_cast<u16x8*>(&tl[ii][cs + 8]) = *reinterpret_cast<const u16x8*>(p + 8);
  }
  __syncthreads();
  const int dr = t & 31, seg = t >> 5;          // seg 0..7
  const int R = (b * 16 + (c0 >> 6)) * 64 + (c0 & 63) + dr;
  u16 tmp[16];
  #pragma unroll
  for(int e = 0; e < 16; ++e) tmp[e] = tl[seg * 16 + e][dr];
  u16* op = vT + (size_t)R * 2048 + i0 + seg * 16;
  *reinterpret_cast<u16x8*>(op)     = *reinterpret_cast<u16x8*>(&tmp[0]);
  *reinterpret_cast<u16x8*>(op + 8) = *reinterpret_cast<u16x8*>(&tmp[8]);
}

// ---------- GEMM: C[M,N] = A[M,K] @ BT[N,K]^T ----------
// MODE 1: f32 out + bf16 residual ; MODE 2: col<2048 -> bf16 qk (stride 2048),
//         col>=2048 -> coalesced v_nat[row][col-2048]
template<int MODE>
__global__ __launch_bounds__(256) void gemm_bt_k(const u16* __restrict__ A, const u16* __restrict__ BT,
                                                 const u16* __restrict__ res, u16* __restrict__ Cb,
                                                 float* __restrict__ Cf, u16* __restrict__ vnat,
                                                 int M, int N, int K){
  __shared__ u16 sA[128 * 32];
  __shared__ u16 sB[128 * 32];
  const int t = threadIdx.x;
  const int row0 = blockIdx.y * 128, col0 = blockIdx.x * 128;
  const int w = t >> 6, lane = t & 63, g = lane >> 4, lq = lane & 15;
  const int wr = (w >> 1) * 64, wc = (w & 1) * 64;
  const int s0 = t, s1 = t + 256;       // 16B staging slots
  f32x4 zero4 = {0.f, 0.f, 0.f, 0.f};
  f32x4 acc[4][4];
  #pragma unroll
  for(int mi = 0; mi < 4; ++mi)
    #pragma unroll
    for(int ni = 0; ni < 4; ++ni) acc[mi][ni] = zero4;

  for(int kt = 0; kt < K; kt += 32){
    gld_lds16(A  + (size_t)(row0 + (s0 >> 2)) * K + kt + (s0 & 3) * 8, &sA[w * 512]);
    gld_lds16(A  + (size_t)(row0 + (s1 >> 2)) * K + kt + (s1 & 3) * 8, &sA[2048 + w * 512]);
    gld_lds16(BT + (size_t)(col0 + (s0 >> 2)) * K + kt + (s0 & 3) * 8, &sB[w * 512]);
    gld_lds16(BT + (size_t)(col0 + (s1 >> 2)) * K + kt + (s1 & 3) * 8, &sB[2048 + w * 512]);
    __syncthreads();
    bf16x8 af[4];
    #pragma unroll
    for(int mi = 0; mi < 4; ++mi)
      af[mi] = *reinterpret_cast<const bf16x8*>(&sA[(wr + mi * 16 + lq) * 32 + g * 8]);
    #pragma unroll
    for(int ni = 0; ni < 4; ++ni){
      bf16x8 bfr = *reinterpret_cast<const bf16x8*>(&sB[(wc + ni * 16 + lq) * 32 + g * 8]);
      #pragma unroll
      for(int mi = 0; mi < 4; ++mi)
        acc[mi][ni] = __builtin_amdgcn_mfma_f32_16x16x32_bf16(af[mi], bfr, acc[mi][ni], 0, 0, 0);
    }
    __syncthreads();
  }
  #pragma unroll
  for(int mi = 0; mi < 4; ++mi)
    #pragma unroll
    for(int ni = 0; ni < 4; ++ni)
      #pragma unroll
      for(int rg = 0; rg < 4; ++rg){
        const int row = row0 + wr + mi * 16 + g * 4 + rg;
        const int col = col0 + wc + ni * 16 + lq;
        float v = acc[mi][ni][rg];
        if(MODE == 1){
          v += bf2f(res[(size_t)row * N + col]);
          Cf[(size_t)row * N + col] = v;
        } else {
          if(col < 2048) Cb[(size_t)row * 2048 + col] = f2bf(v);
          else           vnat[(size_t)row * 1024 + (col - 2048)] = f2bf(v);
        }
      }
}

// ---------- flash attention: S^T form, collapsed BD, no-max softmax, MFMA row-sum ----------
// grid: (S/64, B*H); block 256 = 4 waves, wave w owns q-cols (i) [i0+16w, i0+16w+16)
__global__ __launch_bounds__(256) void attn_k(const u16* __restrict__ qk, const u16* __restrict__ vT,
                                              const float* __restrict__ rw, const float* __restrict__ cc,
                                              u16* __restrict__ av){
  constexpr int S = 2048;
  __shared__ u16 ks[2][64 * 72];    // K tile: rows=key j, cols=d
  __shared__ u16 vs[2][64 * 72];    // V^T tile: rows=d, cols=key j
  __shared__ u16 ps[4][16 * 72];    // per-wave P^T round-trip: rows=i(lq), cols=j
  const int t = threadIdx.x;
  const int i0 = blockIdx.x * 64;
  const int bh = blockIdx.y;                    // b*16 + h
  const int b = bh >> 4, h = bh & 15;
  const int w = t >> 6, lane = t & 63, g = lane >> 4, lq = lane & 15;
  const int iw0 = i0 + w * 16;
  const int i_lane = iw0 + lq;                  // this lane's q row
  const float scale = 0.125f;
  const float L2E = 1.4426950408889634f;

  // Q fragment (B-operand of S^T MFMA): lane holds Q[i=lq][d contig], pre-scaled
  bf16x8 aq0, aq1;
  {
    const u16* qp = qk + (size_t)(i_lane * 2 + b) * 2048 + h * 64;
    u16x8 q0 = *reinterpret_cast<const u16x8*>(qp + g * 8);
    u16x8 q1 = *reinterpret_cast<const u16x8*>(qp + 32 + g * 8);
    const float* rwp = rw + h * 64 + g * 8;
    u16x8 a0, a1;
    #pragma unroll
    for(int e = 0; e < 8; ++e){
      a0[e] = f2bf((bf2f(q0[e]) + rwp[e]) * scale);
      a1[e] = f2bf((bf2f(q1[e]) + rwp[32 + e]) * scale);
    }
    aq0 = *reinterpret_cast<bf16x8*>(&a0);
    aq1 = *reinterpret_cast<bf16x8*>(&a1);
  }
  // per-lane BD constants, pre-multiplied by log2(e) (exp(s+bd) = exp2(s*L2E + bd*L2E))
  const float ciL = cc[(size_t)(i_lane * 2 + b) * 16 + h] * scale * L2E;
  const float cpL = (i_lane + 1 < S) ? cc[(size_t)((i_lane + 1) * 2 + b) * 16 + h] * scale * L2E : 0.0f;

  f32x4 zero4 = {0.f, 0.f, 0.f, 0.f};
  f32x4 acc[4], acc5 = zero4;       // acc[ni] = O^T d-tiles ; acc5 = row-sum via ones-MFMA
  #pragma unroll
  for(int ni = 0; ni < 4; ++ni) acc[ni] = zero4;
  bf16x8 ones;
  {
    u16x8 ob;
    #pragma unroll
    for(int e = 0; e < 8; ++e) ob[e] = 0x3F80;  // bf16 1.0
    ones = *reinterpret_cast<bf16x8*>(&ob);
  }

  const int jr = t >> 2, c0 = (t & 3) * 16;     // staging: row, u16 col offset
  {
    const u16* kp = qk + (size_t)(jr * 2 + b) * 2048 + 1024 + h * 64 + c0;
    *reinterpret_cast<u16x8*>(&ks[0][jr * 72 + c0])     = *reinterpret_cast<const u16x8*>(kp);
    *reinterpret_cast<u16x8*>(&ks[0][jr * 72 + c0 + 8]) = *reinterpret_cast<const u16x8*>(kp + 8);
    const u16* vp = vT + ((size_t)bh * 64 + jr) * 2048 + c0;
    *reinterpret_cast<u16x8*>(&vs[0][jr * 72 + c0])     = *reinterpret_cast<const u16x8*>(vp);
    *reinterpret_cast<u16x8*>(&vs[0][jr * 72 + c0 + 8]) = *reinterpret_cast<const u16x8*>(vp + 8);
  }
  __syncthreads();

  for(int n = 0; n < 32; ++n){
    const int p = n & 1;
    u16x8 k0, k1, v0, v1;
    const bool pre = (n + 1 < 32);
    if(pre){
      const int j0n = (n + 1) * 64;
      const u16* kp = qk + (size_t)((j0n + jr) * 2 + b) * 2048 + 1024 + h * 64 + c0;
      k0 = *reinterpret_cast<const u16x8*>(kp);
      k1 = *reinterpret_cast<const u16x8*>(kp + 8);
      const u16* vp = vT + ((size_t)bh * 64 + jr) * 2048 + j0n + c0;
      v0 = *reinterpret_cast<const u16x8*>(vp);
      v1 = *reinterpret_cast<const u16x8*>(vp + 8);
    }
    const int j0 = n * 64;
    const bool below = (j0 + 63 <= iw0);        // all j <= i for every lane
    const bool above = (j0 >= iw0 + 17);        // all j >= i+2 for every lane
    // S^T = K·Q^T per 16-j tile; exp; pack; write P^T (j-contiguous per lane)
    #pragma unroll
    for(int jt = 0; jt < 4; ++jt){
      f32x4 s4 = zero4;
      bf16x8 b0 = *reinterpret_cast<const bf16x8*>(&ks[p][(jt * 16 + lq) * 72 + g * 8]);
      s4 = __builtin_amdgcn_mfma_f32_16x16x32_bf16(b0, aq0, s4, 0, 0, 0);
      bf16x8 b1 = *reinterpret_cast<const bf16x8*>(&ks[p][(jt * 16 + lq) * 72 + 32 + g * 8]);
      s4 = __builtin_amdgcn_mfma_f32_16x16x32_bf16(b1, aq1, s4, 0, 0, 0);
      float pv[4];
      if(below){
        #pragma unroll
        for(int rg = 0; rg < 4; ++rg)
          pv[rg] = __builtin_amdgcn_exp2f(fmaf(s4[rg], L2E, ciL));
      } else if(above){
        #pragma unroll
        for(int rg = 0; rg < 4; ++rg)
          pv[rg] = __builtin_amdgcn_exp2f(fmaf(s4[rg], L2E, cpL));
      } else {
        #pragma unroll
        for(int rg = 0; rg < 4; ++rg){
          const int j = j0 + jt * 16 + g * 4 + rg;
          const float t1 = (j <= i_lane) ? ciL : cpL;
          const float bdL = (j == i_lane + 1) ? 0.0f : t1;
          pv[rg] = __builtin_amdgcn_exp2f(fmaf(s4[rg], L2E, bdL));
        }
      }
      // truncate-pack 4 j-contiguous bf16 (rsum uses same truncated P -> bias cancels)
      uint2 pk;
      pk.x = __builtin_amdgcn_perm(fbits(pv[1]), fbits(pv[0]), 0x07060302);
      pk.y = __builtin_amdgcn_perm(fbits(pv[3]), fbits(pv[2]), 0x07060302);
      *reinterpret_cast<uint2*>(&ps[w][lq * 72 + jt * 16 + g * 4]) = pk;
    }
    __asm__ __volatile__("s_waitcnt lgkmcnt(0)" ::: "memory");  // per-wave LDS RAW
    bf16x8 ap0 = *reinterpret_cast<const bf16x8*>(&ps[w][lq * 72 + g * 8]);
    bf16x8 ap1 = *reinterpret_cast<const bf16x8*>(&ps[w][lq * 72 + 32 + g * 8]);
    // O^T = V^T · P^T ; row-sum via ones·P^T
    #pragma unroll
    for(int ni = 0; ni < 4; ++ni){
      bf16x8 bv0 = *reinterpret_cast<const bf16x8*>(&vs[p][(ni * 16 + lq) * 72 + g * 8]);
      acc[ni] = __builtin_amdgcn_mfma_f32_16x16x32_bf16(bv0, ap0, acc[ni], 0, 0, 0);
      bf16x8 bv1 = *reinterpret_cast<const bf16x8*>(&vs[p][(ni * 16 + lq) * 72 + 32 + g * 8]);
      acc[ni] = __builtin_amdgcn_mfma_f32_16x16x32_bf16(bv1, ap1, acc[ni], 0, 0, 0);
    }
    acc5 = __builtin_amdgcn_mfma_f32_16x16x32_bf16(ones, ap0, acc5, 0, 0, 0);
    acc5 = __builtin_amdgcn_mfma_f32_16x16x32_bf16(ones, ap1, acc5, 0, 0, 0);
    if(pre){
      const int q2 = p ^ 1;
      *reinterpret_cast<u16x8*>(&ks[q2][jr * 72 + c0])     = k0;
      *reinterpret_cast<u16x8*>(&ks[q2][jr * 72 + c0 + 8]) = k1;
      *reinterpret_cast<u16x8*>(&vs[q2][jr * 72 + c0])     = v0;
      *reinterpret_cast<u16x8*>(&vs[q2][jr * 72 + c0 + 8]) = v1;
    }
    __syncthreads();
  }
  const float rinv = 1.0f / acc5[0];            // all 4 regs identical (ones rows)
  #pragma unroll
  for(int ni = 0; ni < 4; ++ni){
    ushort4 o;
    o.x = f2bf(acc[ni][0] * rinv);
    o.y = f2bf(acc[ni][1] * rinv);
    o.z = f2bf(acc[ni][2] * rinv);
    o.w = f2bf(acc[ni][3] * rinv);
    const int d = ni * 16 + g * 4;
    *reinterpret_cast<ushort4*>(av + (size_t)(i_lane * 2 + b) * 1024 + h * 64 + d) = o;
  }
}

extern "C" void kernel_launch(void* const* d_in, const int* in_sizes, int n_in,
                              void* d_out, int out_size, void* d_ws, size_t ws_size,
                              hipStream_t stream){
  (void)in_sizes; (void)n_in; (void)out_size; (void)ws_size;
  const float* x    = (const float*)d_in[0];
  const float* r    = (const float*)d_in[1];
  const float* rw   = (const float*)d_in[2];
  const float* rr   = (const float*)d_in[3];
  const float* ln_g = (const float*)d_in[4];
  const float* ln_b = (const float*)d_in[5];
  const float* Wqkv = (const float*)d_in[6];
  const float* Wr   = (const float*)d_in[7];
  const float* Wo   = (const float*)d_in[8];
  char* ws = (char*)d_ws;
  u16*   xnb   = (u16*)(ws + 0);                    //  8 MB bf16 [4096,1024]
  u16*   qk    = (u16*)(ws + 8388608);              // 16 MB bf16 [4096,2048] (q | k)
  u16*   av    = (u16*)(ws + 25165824);             //  8 MB bf16 [4096,1024]; doubles as v_nat
  u16*   woT   = (u16*)(ws + 33554432);             //  2 MB bf16 [1024,1024]
  u16*   wqkvT = (u16*)(ws + 35651584);             //  6 MB bf16 [3072,1024]
  u16*   vT    = (u16*)(ws + 41943040);             //  8 MB bf16 [32,64,2048]
  float* rk0   = (float*)(ws + 50331648);           //  4 KB f32 [1024]
  float* cc    = (float*)(ws + 50335744);           // 256 KB f32 [4096,16]
  u16*   vnat  = av;                                // overlay: consumed by vtrans before attn writes av
  float* out   = (float*)d_out;

  transpose_k<<<dim3(96, 32), dim3(32, 8), 0, stream>>>(Wqkv, wqkvT, 1024, 3072);
  transpose_k<<<dim3(32, 32), dim3(32, 8), 0, stream>>>(Wo, woT, 1024, 1024);
  ln_k<<<4096, 256, 0, stream>>>(x, ln_g, ln_b, xnb);
  hipMemsetAsync(rk0, 0, 4096, stream);
  rk0_k<<<dim3(4, 8), 256, 0, stream>>>(r, Wr, rk0);
  gemm_bt_k<2><<<dim3(24, 32), 256, 0, stream>>>(xnb, wqkvT, nullptr, qk, nullptr, vnat, 4096, 3072, 1024);
  vtrans_k<<<dim3(16, 32, 2), 256, 0, stream>>>(vnat, vT);
  c_k<<<1024, 256, 0, stream>>>(qk, rr, rk0, cc);
  attn_k<<<dim3(32, 32), 256, 0, stream>>>(qk, vT, rw, cc, av);
  gemm_bt_k<1><<<dim3(8, 32), 256, 0, stream>>>(av, woT, xnb, nullptr, out, nullptr, 4096, 1024, 1024);
}

// Round 5
// 242.546 us; speedup vs baseline: 1.5689x; 1.0468x over previous
//
#include <hip/hip_runtime.h>

typedef unsigned short u16;
typedef __attribute__((ext_vector_type(8))) __bf16 bf16x8;
typedef __attribute__((ext_vector_type(8))) u16 u16x8;
typedef __attribute__((ext_vector_type(4))) float f32x4;

__device__ __forceinline__ float bf2f(u16 u){
  union { unsigned int i; float f; } v; v.i = ((unsigned int)u) << 16; return v.f;
}
__device__ __forceinline__ u16 f2bf(float f){
  union { float f; unsigned int u; } v; v.f = f;
  unsigned int u = v.u;
  u += 0x7FFFu + ((u >> 16) & 1u);
  return (u16)(u >> 16);
}
__device__ __forceinline__ unsigned fbits(float f){
  union { float f; unsigned u; } v; v.f = f; return v.u;
}
// async global->LDS, 16B per lane; LDS dest = wave-uniform base + lane*16
__device__ __forceinline__ void gld_lds16(const u16* g, u16* l){
  __builtin_amdgcn_global_load_lds((const __attribute__((address_space(1))) unsigned int*)g,
                                   (__attribute__((address_space(3))) unsigned int*)l, 16, 0, 0);
}

// ---------- transpose f32[R,C] -> bf16[C,R], dims multiple of 32 ----------
__global__ __launch_bounds__(256) void transpose_k(const float* __restrict__ in, u16* __restrict__ out,
                                                   int R, int C){
  __shared__ float tile[32][33];
  const int bx = blockIdx.x * 32, by = blockIdx.y * 32;
  const int tx = threadIdx.x, ty = threadIdx.y;   // block (32,8)
  #pragma unroll
  for(int i = 0; i < 32; i += 8)
    tile[ty + i][tx] = in[(size_t)(by + ty + i) * C + bx + tx];
  __syncthreads();
  #pragma unroll
  for(int i = 0; i < 32; i += 8)
    out[(size_t)(bx + ty + i) * R + by + tx] = f2bf(tile[tx][ty + i]);
}

// ---------- LayerNorm rows of 1024: f32 in -> bf16 out ----------
__global__ __launch_bounds__(256) void ln_k(const float* __restrict__ x, const float* __restrict__ gw,
                                            const float* __restrict__ bw, u16* __restrict__ xnb){
  const int row = blockIdx.x, t = threadIdx.x;
  const float* xr = x + (size_t)row * 1024;
  float4 xv = *reinterpret_cast<const float4*>(xr + t * 4);
  float s  = xv.x + xv.y + xv.z + xv.w;
  float s2 = xv.x*xv.x + xv.y*xv.y + xv.z*xv.z + xv.w*xv.w;
  #pragma unroll
  for(int m = 1; m <= 32; m <<= 1){ s += __shfl_xor(s, m, 64); s2 += __shfl_xor(s2, m, 64); }
  __shared__ float red[8];
  const int w = t >> 6, lane = t & 63;
  if(lane == 0){ red[w] = s; red[4 + w] = s2; }
  __syncthreads();
  float S1 = red[0] + red[1] + red[2] + red[3];
  float S2 = red[4] + red[5] + red[6] + red[7];
  float mu = S1 * (1.f/1024.f);
  float var = S2 * (1.f/1024.f) - mu * mu;
  float rstd = rsqrtf(var + 1e-5f);
  float4 gv = *reinterpret_cast<const float4*>(gw + t * 4);
  float4 bv = *reinterpret_cast<const float4*>(bw + t * 4);
  ushort4 o;
  o.x = f2bf((xv.x - mu) * rstd * gv.x + bv.x);
  o.y = f2bf((xv.y - mu) * rstd * gv.y + bv.y);
  o.z = f2bf((xv.z - mu) * rstd * gv.z + bv.z);
  o.w = f2bf((xv.w - mu) * rstd * gv.w + bv.w);
  *reinterpret_cast<ushort4*>(xnb + (size_t)row * 1024 + t * 4) = o;
}

// ---------- rk0 = r @ Wr : [1024], split over d with atomics (rk0 pre-zeroed) ----------
__global__ __launch_bounds__(256) void rk0_k(const float* __restrict__ r, const float* __restrict__ Wr,
                                             float* __restrict__ rk0){
  const int n = blockIdx.x * 256 + threadIdx.x;
  const int d0 = blockIdx.y * 128;
  float acc = 0.f;
  for(int d = d0; d < d0 + 128; ++d)
    acc += r[d] * Wr[(size_t)d * 1024 + n];
  atomicAdd(&rk0[n], acc);
}

// ---------- c[ib][h] = sum_d (q + rr) * rk0 ; one wave per ib ----------
__global__ __launch_bounds__(256) void c_k(const u16* __restrict__ qk, const float* __restrict__ rr,
                                           const float* __restrict__ rk0, float* __restrict__ cc){
  const int w = threadIdx.x >> 6, lane = threadIdx.x & 63;
  const int ib = blockIdx.x * 4 + w;
  const u16* qp = qk + (size_t)ib * 2048 + lane * 16;
  u16x8 q0 = *reinterpret_cast<const u16x8*>(qp);
  u16x8 q1 = *reinterpret_cast<const u16x8*>(qp + 8);
  const float* rrp = rr + lane * 16;
  const float* rkp = rk0 + lane * 16;
  float s = 0.f;
  #pragma unroll
  for(int e = 0; e < 8; ++e){
    s += (bf2f(q0[e]) + rrp[e]) * rkp[e];
    s += (bf2f(q1[e]) + rrp[8 + e]) * rkp[8 + e];
  }
  s += __shfl_xor(s, 1, 64);
  s += __shfl_xor(s, 2, 64);
  if((lane & 3) == 0) cc[(size_t)ib * 16 + (lane >> 2)] = s;
}

// ---------- V transpose: v_nat[i*2+b][h*64+d] -> vT[(b*16+h)*64+d][i] ----------
__global__ __launch_bounds__(256) void vtrans_k(const u16* __restrict__ vnat, u16* __restrict__ vT){
  __shared__ u16 tl[128][40];
  const int t = threadIdx.x;
  const int i0 = blockIdx.x * 128, c0 = blockIdx.y * 32, b = blockIdx.z;
  {
    const int ii = t & 127, cs = (t >> 7) * 16;
    const u16* p = vnat + (size_t)((i0 + ii) * 2 + b) * 1024 + c0 + cs;
    *reinterpret_cast<u16x8*>(&tl[ii][cs])     = *reinterpret_cast<const u16x8*>(p);
    *reinterpret_cast<u16x8*>(&tl[ii][cs + 8]) = *reinterpret_cast<const u16x8*>(p + 8);
  }
  __syncthreads();
  const int dr = t & 31, seg = t >> 5;          // seg 0..7
  const int R = (b * 16 + (c0 >> 6)) * 64 + (c0 & 63) + dr;
  u16 tmp[16];
  #pragma unroll
  for(int e = 0; e < 16; ++e) tmp[e] = tl[seg * 16 + e][dr];
  u16* op = vT + (size_t)R * 2048 + i0 + seg * 16;
  *reinterpret_cast<u16x8*>(op)     = *reinterpret_cast<u16x8*>(&tmp[0]);
  *reinterpret_cast<u16x8*>(op + 8) = *reinterpret_cast<u16x8*>(&tmp[8]);
}

// ---------- GEMM: C[M,N] = A[M,K] @ BT[N,K]^T ----------
// MODE 1: f32 out + bf16 residual ; MODE 2: col<2048 -> bf16 qk (stride 2048),
//         col>=2048 -> coalesced v_nat[row][col-2048]
template<int MODE>
__global__ __launch_bounds__(256) void gemm_bt_k(const u16* __restrict__ A, const u16* __restrict__ BT,
                                                 const u16* __restrict__ res, u16* __restrict__ Cb,
                                                 float* __restrict__ Cf, u16* __restrict__ vnat,
                                                 int M, int N, int K){
  __shared__ u16 sA[128 * 32];
  __shared__ u16 sB[128 * 32];
  const int t = threadIdx.x;
  const int row0 = blockIdx.y * 128, col0 = blockIdx.x * 128;
  const int w = t >> 6, lane = t & 63, g = lane >> 4, lq = lane & 15;
  const int wr = (w >> 1) * 64, wc = (w & 1) * 64;
  const int s0 = t, s1 = t + 256;       // 16B staging slots
  f32x4 zero4 = {0.f, 0.f, 0.f, 0.f};
  f32x4 acc[4][4];
  #pragma unroll
  for(int mi = 0; mi < 4; ++mi)
    #pragma unroll
    for(int ni = 0; ni < 4; ++ni) acc[mi][ni] = zero4;

  for(int kt = 0; kt < K; kt += 32){
    gld_lds16(A  + (size_t)(row0 + (s0 >> 2)) * K + kt + (s0 & 3) * 8, &sA[w * 512]);
    gld_lds16(A  + (size_t)(row0 + (s1 >> 2)) * K + kt + (s1 & 3) * 8, &sA[2048 + w * 512]);
    gld_lds16(BT + (size_t)(col0 + (s0 >> 2)) * K + kt + (s0 & 3) * 8, &sB[w * 512]);
    gld_lds16(BT + (size_t)(col0 + (s1 >> 2)) * K + kt + (s1 & 3) * 8, &sB[2048 + w * 512]);
    __syncthreads();
    bf16x8 af[4];
    #pragma unroll
    for(int mi = 0; mi < 4; ++mi)
      af[mi] = *reinterpret_cast<const bf16x8*>(&sA[(wr + mi * 16 + lq) * 32 + g * 8]);
    #pragma unroll
    for(int ni = 0; ni < 4; ++ni){
      bf16x8 bfr = *reinterpret_cast<const bf16x8*>(&sB[(wc + ni * 16 + lq) * 32 + g * 8]);
      #pragma unroll
      for(int mi = 0; mi < 4; ++mi)
        acc[mi][ni] = __builtin_amdgcn_mfma_f32_16x16x32_bf16(af[mi], bfr, acc[mi][ni], 0, 0, 0);
    }
    __syncthreads();
  }
  #pragma unroll
  for(int mi = 0; mi < 4; ++mi)
    #pragma unroll
    for(int ni = 0; ni < 4; ++ni)
      #pragma unroll
      for(int rg = 0; rg < 4; ++rg){
        const int row = row0 + wr + mi * 16 + g * 4 + rg;
        const int col = col0 + wc + ni * 16 + lq;
        float v = acc[mi][ni][rg];
        if(MODE == 1){
          v += bf2f(res[(size_t)row * N + col]);
          Cf[(size_t)row * N + col] = v;
        } else {
          if(col < 2048) Cb[(size_t)row * 2048 + col] = f2bf(v);
          else           vnat[(size_t)row * 1024 + (col - 2048)] = f2bf(v);
        }
      }
}

// ---------- flash attention: S^T form, collapsed BD, no-max softmax, MFMA row-sum ----------
// grid: (S/128, B*H); block 256 = 4 waves; wave w owns 32 q-rows [i0+32w, i0+32w+32)
// K/V fragment reads are i-invariant -> amortized over 2 i-tiles per wave.
__global__ __launch_bounds__(256) void attn_k(const u16* __restrict__ qk, const u16* __restrict__ vT,
                                              const float* __restrict__ rw, const float* __restrict__ cc,
                                              u16* __restrict__ av){
  constexpr int S = 2048;
  __shared__ u16 ks[2][64 * 72];    // K tile: rows=key j, cols=d
  __shared__ u16 vs[2][64 * 72];    // V^T tile: rows=d, cols=key j
  __shared__ u16 ps[4][32 * 72];    // per-wave P^T round-trip: rows=i (32), cols=j
  const int t = threadIdx.x;
  const int i0 = blockIdx.x * 128;
  const int bh = blockIdx.y;                    // b*16 + h
  const int b = bh >> 4, h = bh & 15;
  const int w = t >> 6, lane = t & 63, g = lane >> 4, lq = lane & 15;
  const int iw0 = i0 + w * 32;
  const float scale = 0.125f;
  const float L2E = 1.4426950408889634f;

  // Q fragments (B-operand of S^T MFMA), 2 i-tiles per wave, pre-scaled
  bf16x8 aq[2][2];
  int ilane[2];
  float ciL[2], cpL[2];
  #pragma unroll
  for(int u = 0; u < 2; ++u){
    ilane[u] = iw0 + u * 16 + lq;
    const u16* qp = qk + (size_t)(ilane[u] * 2 + b) * 2048 + h * 64;
    u16x8 q0 = *reinterpret_cast<const u16x8*>(qp + g * 8);
    u16x8 q1 = *reinterpret_cast<const u16x8*>(qp + 32 + g * 8);
    const float* rwp = rw + h * 64 + g * 8;
    u16x8 a0, a1;
    #pragma unroll
    for(int e = 0; e < 8; ++e){
      a0[e] = f2bf((bf2f(q0[e]) + rwp[e]) * scale);
      a1[e] = f2bf((bf2f(q1[e]) + rwp[32 + e]) * scale);
    }
    aq[u][0] = *reinterpret_cast<bf16x8*>(&a0);
    aq[u][1] = *reinterpret_cast<bf16x8*>(&a1);
    ciL[u] = cc[(size_t)(ilane[u] * 2 + b) * 16 + h] * scale * L2E;
    cpL[u] = (ilane[u] + 1 < S) ? cc[(size_t)((ilane[u] + 1) * 2 + b) * 16 + h] * scale * L2E : 0.0f;
  }

  f32x4 zero4 = {0.f, 0.f, 0.f, 0.f};
  f32x4 acc[2][4], acc5[2];
  #pragma unroll
  for(int u = 0; u < 2; ++u){
    acc5[u] = zero4;
    #pragma unroll
    for(int ni = 0; ni < 4; ++ni) acc[u][ni] = zero4;
  }
  bf16x8 ones;
  {
    u16x8 ob;
    #pragma unroll
    for(int e = 0; e < 8; ++e) ob[e] = 0x3F80;  // bf16 1.0
    ones = *reinterpret_cast<bf16x8*>(&ob);
  }

  const int jr = t >> 2, c0 = (t & 3) * 16;     // staging: row, u16 col offset
  {
    const u16* kp = qk + (size_t)(jr * 2 + b) * 2048 + 1024 + h * 64 + c0;
    *reinterpret_cast<u16x8*>(&ks[0][jr * 72 + c0])     = *reinterpret_cast<const u16x8*>(kp);
    *reinterpret_cast<u16x8*>(&ks[0][jr * 72 + c0 + 8]) = *reinterpret_cast<const u16x8*>(kp + 8);
    const u16* vp = vT + ((size_t)bh * 64 + jr) * 2048 + c0;
    *reinterpret_cast<u16x8*>(&vs[0][jr * 72 + c0])     = *reinterpret_cast<const u16x8*>(vp);
    *reinterpret_cast<u16x8*>(&vs[0][jr * 72 + c0 + 8]) = *reinterpret_cast<const u16x8*>(vp + 8);
  }
  __syncthreads();

  for(int n = 0; n < 32; ++n){
    const int p = n & 1;
    u16x8 k0, k1, v0, v1;
    const bool pre = (n + 1 < 32);
    if(pre){
      const int j0n = (n + 1) * 64;
      const u16* kp = qk + (size_t)((j0n + jr) * 2 + b) * 2048 + 1024 + h * 64 + c0;
      k0 = *reinterpret_cast<const u16x8*>(kp);
      k1 = *reinterpret_cast<const u16x8*>(kp + 8);
      const u16* vp = vT + ((size_t)bh * 64 + jr) * 2048 + j0n + c0;
      v0 = *reinterpret_cast<const u16x8*>(vp);
      v1 = *reinterpret_cast<const u16x8*>(vp + 8);
    }
    const int j0 = n * 64;
    // S^T = K·Q^T per 16-j tile; K frags shared across the 2 i-tiles
    #pragma unroll
    for(int jt = 0; jt < 4; ++jt){
      bf16x8 b0 = *reinterpret_cast<const bf16x8*>(&ks[p][(jt * 16 + lq) * 72 + g * 8]);
      bf16x8 b1 = *reinterpret_cast<const bf16x8*>(&ks[p][(jt * 16 + lq) * 72 + 32 + g * 8]);
      #pragma unroll
      for(int u = 0; u < 2; ++u){
        const int iwu = iw0 + u * 16;
        f32x4 s4 = zero4;
        s4 = __builtin_amdgcn_mfma_f32_16x16x32_bf16(b0, aq[u][0], s4, 0, 0, 0);
        s4 = __builtin_amdgcn_mfma_f32_16x16x32_bf16(b1, aq[u][1], s4, 0, 0, 0);
        float pv[4];
        if(j0 + 63 <= iwu){                     // all j <= i
          #pragma unroll
          for(int rg = 0; rg < 4; ++rg)
            pv[rg] = __builtin_amdgcn_exp2f(fmaf(s4[rg], L2E, ciL[u]));
        } else if(j0 >= iwu + 17){              // all j >= i+2
          #pragma unroll
          for(int rg = 0; rg < 4; ++rg)
            pv[rg] = __builtin_amdgcn_exp2f(fmaf(s4[rg], L2E, cpL[u]));
        } else {
          #pragma unroll
          for(int rg = 0; rg < 4; ++rg){
            const int j = j0 + jt * 16 + g * 4 + rg;
            const float t1 = (j <= ilane[u]) ? ciL[u] : cpL[u];
            const float bdL = (j == ilane[u] + 1) ? 0.0f : t1;
            pv[rg] = __builtin_amdgcn_exp2f(fmaf(s4[rg], L2E, bdL));
          }
        }
        uint2 pk;
        pk.x = __builtin_amdgcn_perm(fbits(pv[1]), fbits(pv[0]), 0x07060302);
        pk.y = __builtin_amdgcn_perm(fbits(pv[3]), fbits(pv[2]), 0x07060302);
        *reinterpret_cast<uint2*>(&ps[w][(u * 16 + lq) * 72 + jt * 16 + g * 4]) = pk;
      }
    }
    __asm__ __volatile__("s_waitcnt lgkmcnt(0)" ::: "memory");  // per-wave LDS RAW
    bf16x8 ap[2][2];
    #pragma unroll
    for(int u = 0; u < 2; ++u){
      ap[u][0] = *reinterpret_cast<const bf16x8*>(&ps[w][(u * 16 + lq) * 72 + g * 8]);
      ap[u][1] = *reinterpret_cast<const bf16x8*>(&ps[w][(u * 16 + lq) * 72 + 32 + g * 8]);
    }
    // O^T = V^T · P^T ; V frags shared across the 2 i-tiles ; row-sum via ones·P^T
    #pragma unroll
    for(int ni = 0; ni < 4; ++ni){
      bf16x8 bv0 = *reinterpret_cast<const bf16x8*>(&vs[p][(ni * 16 + lq) * 72 + g * 8]);
      bf16x8 bv1 = *reinterpret_cast<const bf16x8*>(&vs[p][(ni * 16 + lq) * 72 + 32 + g * 8]);
      #pragma unroll
      for(int u = 0; u < 2; ++u){
        acc[u][ni] = __builtin_amdgcn_mfma_f32_16x16x32_bf16(bv0, ap[u][0], acc[u][ni], 0, 0, 0);
        acc[u][ni] = __builtin_amdgcn_mfma_f32_16x16x32_bf16(bv1, ap[u][1], acc[u][ni], 0, 0, 0);
      }
    }
    #pragma unroll
    for(int u = 0; u < 2; ++u){
      acc5[u] = __builtin_amdgcn_mfma_f32_16x16x32_bf16(ones, ap[u][0], acc5[u], 0, 0, 0);
      acc5[u] = __builtin_amdgcn_mfma_f32_16x16x32_bf16(ones, ap[u][1], acc5[u], 0, 0, 0);
    }
    if(pre){
      const int q2 = p ^ 1;
      *reinterpret_cast<u16x8*>(&ks[q2][jr * 72 + c0])     = k0;
      *reinterpret_cast<u16x8*>(&ks[q2][jr * 72 + c0 + 8]) = k1;
      *reinterpret_cast<u16x8*>(&vs[q2][jr * 72 + c0])     = v0;
      *reinterpret_cast<u16x8*>(&vs[q2][jr * 72 + c0 + 8]) = v1;
    }
    __syncthreads();
  }
  #pragma unroll
  for(int u = 0; u < 2; ++u){
    const float rinv = 1.0f / acc5[u][0];       // all 4 regs identical (ones rows)
    #pragma unroll
    for(int ni = 0; ni < 4; ++ni){
      ushort4 o;
      o.x = f2bf(acc[u][ni][0] * rinv);
      o.y = f2bf(acc[u][ni][1] * rinv);
      o.z = f2bf(acc[u][ni][2] * rinv);
      o.w = f2bf(acc[u][ni][3] * rinv);
      const int d = ni * 16 + g * 4;
      *reinterpret_cast<ushort4*>(av + (size_t)(ilane[u] * 2 + b) * 1024 + h * 64 + d) = o;
    }
  }
}

extern "C" void kernel_launch(void* const* d_in, const int* in_sizes, int n_in,
                              void* d_out, int out_size, void* d_ws, size_t ws_size,
                              hipStream_t stream){
  (void)in_sizes; (void)n_in; (void)out_size; (void)ws_size;
  const float* x    = (const float*)d_in[0];
  const float* r    = (const float*)d_in[1];
  const float* rw   = (const float*)d_in[2];
  const float* rr   = (const float*)d_in[3];
  const float* ln_g = (const float*)d_in[4];
  const float* ln_b = (const float*)d_in[5];
  const float* Wqkv = (const float*)d_in[6];
  const float* Wr   = (const float*)d_in[7];
  const float* Wo   = (const float*)d_in[8];
  char* ws = (char*)d_ws;
  u16*   xnb   = (u16*)(ws + 0);                    //  8 MB bf16 [4096,1024]
  u16*   qk    = (u16*)(ws + 8388608);              // 16 MB bf16 [4096,2048] (q | k)
  u16*   av    = (u16*)(ws + 25165824);             //  8 MB bf16 [4096,1024]; doubles as v_nat
  u16*   woT   = (u16*)(ws + 33554432);             //  2 MB bf16 [1024,1024]
  u16*   wqkvT = (u16*)(ws + 35651584);             //  6 MB bf16 [3072,1024]
  u16*   vT    = (u16*)(ws + 41943040);             //  8 MB bf16 [32,64,2048]
  float* rk0   = (float*)(ws + 50331648);           //  4 KB f32 [1024]
  float* cc    = (float*)(ws + 50335744);           // 256 KB f32 [4096,16]
  u16*   vnat  = av;                                // overlay: consumed by vtrans before attn writes av
  float* out   = (float*)d_out;

  transpose_k<<<dim3(96, 32), dim3(32, 8), 0, stream>>>(Wqkv, wqkvT, 1024, 3072);
  transpose_k<<<dim3(32, 32), dim3(32, 8), 0, stream>>>(Wo, woT, 1024, 1024);
  ln_k<<<4096, 256, 0, stream>>>(x, ln_g, ln_b, xnb);
  hipMemsetAsync(rk0, 0, 4096, stream);
  rk0_k<<<dim3(4, 8), 256, 0, stream>>>(r, Wr, rk0);
  gemm_bt_k<2><<<dim3(24, 32), 256, 0, stream>>>(xnb, wqkvT, nullptr, qk, nullptr, vnat, 4096, 3072, 1024);
  vtrans_k<<<dim3(16, 32, 2), 256, 0, stream>>>(vnat, vT);
  c_k<<<1024, 256, 0, stream>>>(qk, rr, rk0, cc);
  attn_k<<<dim3(16, 32), 256, 0, stream>>>(qk, vT, rw, cc, av);
  gemm_bt_k<1><<<dim3(8, 32), 256, 0, stream>>>(av, woT, xnb, nullptr, out, nullptr, 4096, 1024, 1024);
}

// Round 6
// 236.022 us; speedup vs baseline: 1.6123x; 1.0276x over previous
//
#include <hip/hip_runtime.h>

typedef unsigned short u16;
typedef __attribute__((ext_vector_type(8))) __bf16 bf16x8;
typedef __attribute__((ext_vector_type(8))) u16 u16x8;
typedef __attribute__((ext_vector_type(4))) float f32x4;
typedef __attribute__((ext_vector_type(16))) float f32x16;

__device__ __forceinline__ float bf2f(u16 u){
  union { unsigned int i; float f; } v; v.i = ((unsigned int)u) << 16; return v.f;
}
__device__ __forceinline__ u16 f2bf(float f){
  union { float f; unsigned int u; } v; v.f = f;
  unsigned int u = v.u;
  u += 0x7FFFu + ((u >> 16) & 1u);
  return (u16)(u >> 16);
}
__device__ __forceinline__ unsigned fbits(float f){
  union { float f; unsigned u; } v; v.f = f; return v.u;
}
// async global->LDS, 16B per lane; LDS dest = wave-uniform base + lane*16
__device__ __forceinline__ void gld_lds16(const u16* g, u16* l){
  __builtin_amdgcn_global_load_lds((const __attribute__((address_space(1))) unsigned int*)g,
                                   (__attribute__((address_space(3))) unsigned int*)l, 16, 0, 0);
}

// ---------- transpose f32[R,C] -> bf16[C,R], dims multiple of 32 ----------
__global__ __launch_bounds__(256) void transpose_k(const float* __restrict__ in, u16* __restrict__ out,
                                                   int R, int C){
  __shared__ float tile[32][33];
  const int bx = blockIdx.x * 32, by = blockIdx.y * 32;
  const int tx = threadIdx.x, ty = threadIdx.y;   // block (32,8)
  #pragma unroll
  for(int i = 0; i < 32; i += 8)
    tile[ty + i][tx] = in[(size_t)(by + ty + i) * C + bx + tx];
  __syncthreads();
  #pragma unroll
  for(int i = 0; i < 32; i += 8)
    out[(size_t)(bx + ty + i) * R + by + tx] = f2bf(tile[tx][ty + i]);
}

// ---------- LayerNorm rows of 1024: f32 in -> bf16 out ----------
__global__ __launch_bounds__(256) void ln_k(const float* __restrict__ x, const float* __restrict__ gw,
                                            const float* __restrict__ bw, u16* __restrict__ xnb){
  const int row = blockIdx.x, t = threadIdx.x;
  const float* xr = x + (size_t)row * 1024;
  float4 xv = *reinterpret_cast<const float4*>(xr + t * 4);
  float s  = xv.x + xv.y + xv.z + xv.w;
  float s2 = xv.x*xv.x + xv.y*xv.y + xv.z*xv.z + xv.w*xv.w;
  #pragma unroll
  for(int m = 1; m <= 32; m <<= 1){ s += __shfl_xor(s, m, 64); s2 += __shfl_xor(s2, m, 64); }
  __shared__ float red[8];
  const int w = t >> 6, lane = t & 63;
  if(lane == 0){ red[w] = s; red[4 + w] = s2; }
  __syncthreads();
  float S1 = red[0] + red[1] + red[2] + red[3];
  float S2 = red[4] + red[5] + red[6] + red[7];
  float mu = S1 * (1.f/1024.f);
  float var = S2 * (1.f/1024.f) - mu * mu;
  float rstd = rsqrtf(var + 1e-5f);
  float4 gv = *reinterpret_cast<const float4*>(gw + t * 4);
  float4 bv = *reinterpret_cast<const float4*>(bw + t * 4);
  ushort4 o;
  o.x = f2bf((xv.x - mu) * rstd * gv.x + bv.x);
  o.y = f2bf((xv.y - mu) * rstd * gv.y + bv.y);
  o.z = f2bf((xv.z - mu) * rstd * gv.z + bv.z);
  o.w = f2bf((xv.w - mu) * rstd * gv.w + bv.w);
  *reinterpret_cast<ushort4*>(xnb + (size_t)row * 1024 + t * 4) = o;
}

// ---------- rk0 = r @ Wr : [1024], split over d with atomics (rk0 pre-zeroed) ----------
__global__ __launch_bounds__(256) void rk0_k(const float* __restrict__ r, const float* __restrict__ Wr,
                                             float* __restrict__ rk0){
  const int n = blockIdx.x * 256 + threadIdx.x;
  const int d0 = blockIdx.y * 128;
  float acc = 0.f;
  for(int d = d0; d < d0 + 128; ++d)
    acc += r[d] * Wr[(size_t)d * 1024 + n];
  atomicAdd(&rk0[n], acc);
}

// ---------- c[ib][h] = sum_d (q + rr) * rk0 ; one wave per ib ----------
__global__ __launch_bounds__(256) void c_k(const u16* __restrict__ qk, const float* __restrict__ rr,
                                           const float* __restrict__ rk0, float* __restrict__ cc){
  const int w = threadIdx.x >> 6, lane = threadIdx.x & 63;
  const int ib = blockIdx.x * 4 + w;
  const u16* qp = qk + (size_t)ib * 2048 + lane * 16;
  u16x8 q0 = *reinterpret_cast<const u16x8*>(qp);
  u16x8 q1 = *reinterpret_cast<const u16x8*>(qp + 8);
  const float* rrp = rr + lane * 16;
  const float* rkp = rk0 + lane * 16;
  float s = 0.f;
  #pragma unroll
  for(int e = 0; e < 8; ++e){
    s += (bf2f(q0[e]) + rrp[e]) * rkp[e];
    s += (bf2f(q1[e]) + rrp[8 + e]) * rkp[8 + e];
  }
  s += __shfl_xor(s, 1, 64);
  s += __shfl_xor(s, 2, 64);
  if((lane & 3) == 0) cc[(size_t)ib * 16 + (lane >> 2)] = s;
}

// ---------- V transpose: v_nat[i*2+b][h*64+d] -> vT[(b*16+h)*64+d][i] ----------
__global__ __launch_bounds__(256) void vtrans_k(const u16* __restrict__ vnat, u16* __restrict__ vT){
  __shared__ u16 tl[128][40];
  const int t = threadIdx.x;
  const int i0 = blockIdx.x * 128, c0 = blockIdx.y * 32, b = blockIdx.z;
  {
    const int ii = t & 127, cs = (t >> 7) * 16;
    const u16* p = vnat + (size_t)((i0 + ii) * 2 + b) * 1024 + c0 + cs;
    *reinterpret_cast<u16x8*>(&tl[ii][cs])     = *reinterpret_cast<const u16x8*>(p);
    *reinterpret_cast<u16x8*>(&tl[ii][cs + 8]) = *reinterpret_cast<const u16x8*>(p + 8);
  }
  __syncthreads();
  const int dr = t & 31, seg = t >> 5;          // seg 0..7
  const int R = (b * 16 + (c0 >> 6)) * 64 + (c0 & 63) + dr;
  u16 tmp[16];
  #pragma unroll
  for(int e = 0; e < 16; ++e) tmp[e] = tl[seg * 16 + e][dr];
  u16* op = vT + (size_t)R * 2048 + i0 + seg * 16;
  *reinterpret_cast<u16x8*>(op)     = *reinterpret_cast<u16x8*>(&tmp[0]);
  *reinterpret_cast<u16x8*>(op + 8) = *reinterpret_cast<u16x8*>(&tmp[8]);
}

// ---------- GEMM: C[M,N] = A[M,K] @ BT[N,K]^T ----------
// MODE 1: f32 out + bf16 residual ; MODE 2: col<2048 -> bf16 qk (stride 2048),
//         col>=2048 -> coalesced v_nat[row][col-2048]
template<int MODE>
__global__ __launch_bounds__(256) void gemm_bt_k(const u16* __restrict__ A, const u16* __restrict__ BT,
                                                 const u16* __restrict__ res, u16* __restrict__ Cb,
                                                 float* __restrict__ Cf, u16* __restrict__ vnat,
                                                 int M, int N, int K){
  __shared__ u16 sA[128 * 32];
  __shared__ u16 sB[128 * 32];
  const int t = threadIdx.x;
  const int row0 = blockIdx.y * 128, col0 = blockIdx.x * 128;
  const int w = t >> 6, lane = t & 63, g = lane >> 4, lq = lane & 15;
  const int wr = (w >> 1) * 64, wc = (w & 1) * 64;
  const int s0 = t, s1 = t + 256;       // 16B staging slots
  f32x4 zero4 = {0.f, 0.f, 0.f, 0.f};
  f32x4 acc[4][4];
  #pragma unroll
  for(int mi = 0; mi < 4; ++mi)
    #pragma unroll
    for(int ni = 0; ni < 4; ++ni) acc[mi][ni] = zero4;

  for(int kt = 0; kt < K; kt += 32){
    gld_lds16(A  + (size_t)(row0 + (s0 >> 2)) * K + kt + (s0 & 3) * 8, &sA[w * 512]);
    gld_lds16(A  + (size_t)(row0 + (s1 >> 2)) * K + kt + (s1 & 3) * 8, &sA[2048 + w * 512]);
    gld_lds16(BT + (size_t)(col0 + (s0 >> 2)) * K + kt + (s0 & 3) * 8, &sB[w * 512]);
    gld_lds16(BT + (size_t)(col0 + (s1 >> 2)) * K + kt + (s1 & 3) * 8, &sB[2048 + w * 512]);
    __syncthreads();
    bf16x8 af[4];
    #pragma unroll
    for(int mi = 0; mi < 4; ++mi)
      af[mi] = *reinterpret_cast<const bf16x8*>(&sA[(wr + mi * 16 + lq) * 32 + g * 8]);
    #pragma unroll
    for(int ni = 0; ni < 4; ++ni){
      bf16x8 bfr = *reinterpret_cast<const bf16x8*>(&sB[(wc + ni * 16 + lq) * 32 + g * 8]);
      #pragma unroll
      for(int mi = 0; mi < 4; ++mi)
        acc[mi][ni] = __builtin_amdgcn_mfma_f32_16x16x32_bf16(af[mi], bfr, acc[mi][ni], 0, 0, 0);
    }
    __syncthreads();
  }
  #pragma unroll
  for(int mi = 0; mi < 4; ++mi)
    #pragma unroll
    for(int ni = 0; ni < 4; ++ni)
      #pragma unroll
      for(int rg = 0; rg < 4; ++rg){
        const int row = row0 + wr + mi * 16 + g * 4 + rg;
        const int col = col0 + wc + ni * 16 + lq;
        float v = acc[mi][ni][rg];
        if(MODE == 1){
          v += bf2f(res[(size_t)row * N + col]);
          Cf[(size_t)row * N + col] = v;
        } else {
          if(col < 2048) Cb[(size_t)row * 2048 + col] = f2bf(v);
          else           vnat[(size_t)row * 1024 + (col - 2048)] = f2bf(v);
        }
      }
}

// ---------- flash attention: 32x32x16 MFMA, S^T form, shfl-exchange P (no ps LDS) ----------
// grid: (S/128, B*H); block 256 = 4 waves; wave w owns 32 q-rows [i0+32w, i0+32w+32)
// S^T C-layout: col i = lane&31, row j = (r&3)+8*(r>>2)+4*(lane>>5)
// PV B-operand: n = lane&31, k = (lane>>5)*8+e  -> one lane^32 exchange per 16-j k-tile
__global__ __launch_bounds__(256) void attn_k(const u16* __restrict__ qk, const u16* __restrict__ vT,
                                              const float* __restrict__ rw, const float* __restrict__ cc,
                                              u16* __restrict__ av){
  constexpr int S = 2048, ST = 74;  // 37 dwords row stride: bank = (5m+4q5)%32, 2-way free
  __shared__ u16 ks[2][64 * ST];    // K tile: rows=key j, cols=d
  __shared__ u16 vs[2][64 * ST];    // V^T tile: rows=d, cols=key j
  const int t = threadIdx.x;
  const int i0 = blockIdx.x * 128;
  const int bh = blockIdx.y;                    // b*16 + h
  const int b = bh >> 4, h = bh & 15;
  const int w = t >> 6, lane = t & 63, m = lane & 31, q5 = lane >> 5;
  const int iw0 = i0 + w * 32;
  const int i_lane = iw0 + m;
  const float SC = 0.125f * 1.4426950408889634f;   // scale * log2(e): exp(x)=exp2(SC-domain)

  // Q B-frags (loop-invariant): lane holds Q[i=m][d=kt*16+q5*8+e], pre-scaled by SC
  bf16x8 qf[4];
  {
    const u16* qp = qk + (size_t)(i_lane * 2 + b) * 2048 + h * 64;
    const float* rwp = rw + h * 64;
    #pragma unroll
    for(int kt = 0; kt < 4; ++kt){
      const int dbase = kt * 16 + q5 * 8;
      u16x8 qv = *reinterpret_cast<const u16x8*>(qp + dbase);
      u16x8 a;
      #pragma unroll
      for(int e = 0; e < 8; ++e) a[e] = f2bf((bf2f(qv[e]) + rwp[dbase + e]) * SC);
      qf[kt] = *reinterpret_cast<bf16x8*>(&a);
    }
  }
  const float ciL = cc[(size_t)(i_lane * 2 + b) * 16 + h] * SC;
  const float cpL = (i_lane + 1 < S) ? cc[(size_t)((i_lane + 1) * 2 + b) * 16 + h] * SC : 0.0f;

  f32x16 acc0, acc1, z16;
  #pragma unroll
  for(int e = 0; e < 16; ++e) z16[e] = 0.f;
  acc0 = z16; acc1 = z16;
  float rsum = 0.f;

  const int jr = t >> 2, c0 = (t & 3) * 16;     // staging: row, u16 col offset
  {
    const u16* kp = qk + (size_t)(jr * 2 + b) * 2048 + 1024 + h * 64 + c0;
    *reinterpret_cast<u16x8*>(&ks[0][jr * ST + c0])     = *reinterpret_cast<const u16x8*>(kp);
    *reinterpret_cast<u16x8*>(&ks[0][jr * ST + c0 + 8]) = *reinterpret_cast<const u16x8*>(kp + 8);
    const u16* vp = vT + ((size_t)bh * 64 + jr) * 2048 + c0;
    *reinterpret_cast<u16x8*>(&vs[0][jr * ST + c0])     = *reinterpret_cast<const u16x8*>(vp);
    *reinterpret_cast<u16x8*>(&vs[0][jr * ST + c0 + 8]) = *reinterpret_cast<const u16x8*>(vp + 8);
  }
  __syncthreads();

  for(int n = 0; n < 32; ++n){
    const int p = n & 1;
    u16x8 k0, k1, v0, v1;
    const bool pre = (n + 1 < 32);
    if(pre){
      const int j0n = (n + 1) * 64;
      const u16* kp = qk + (size_t)((j0n + jr) * 2 + b) * 2048 + 1024 + h * 64 + c0;
      k0 = *reinterpret_cast<const u16x8*>(kp);
      k1 = *reinterpret_cast<const u16x8*>(kp + 8);
      const u16* vp = vT + ((size_t)bh * 64 + jr) * 2048 + j0n + c0;
      v0 = *reinterpret_cast<const u16x8*>(vp);
      v1 = *reinterpret_cast<const u16x8*>(vp + 8);
    }
    const int j0 = n * 64;
    bf16x8 pfrag[4];                            // PV B-frags for the 4 16-j k-tiles
    #pragma unroll
    for(int jt = 0; jt < 2; ++jt){
      const int tj0 = j0 + jt * 32;
      f32x16 s = z16;
      #pragma unroll
      for(int kt = 0; kt < 4; ++kt){
        bf16x8 ka = *reinterpret_cast<const bf16x8*>(&ks[p][(jt * 32 + m) * ST + kt * 16 + q5 * 8]);
        s = __builtin_amdgcn_mfma_f32_32x32x16_bf16(ka, qf[kt], s, 0, 0, 0);
      }
      // exp2(s + bd) ; bd = ciL (j<=i), 0 (j==i+1), cpL (j>=i+2)
      float pv[16];
      if(tj0 + 31 <= iw0){                      // whole tile below diagonal for all lanes
        #pragma unroll
        for(int r = 0; r < 16; ++r) pv[r] = __builtin_amdgcn_exp2f(s[r] + ciL);
      } else if(tj0 >= iw0 + 33){               // whole tile above
        #pragma unroll
        for(int r = 0; r < 16; ++r) pv[r] = __builtin_amdgcn_exp2f(s[r] + cpL);
      } else {
        #pragma unroll
        for(int r = 0; r < 16; ++r){
          const int j = tj0 + (r & 3) + 8 * (r >> 2) + 4 * q5;
          const float t1 = (j <= i_lane) ? ciL : cpL;
          const float bdL = (j == i_lane + 1) ? 0.0f : t1;
          pv[r] = __builtin_amdgcn_exp2f(s[r] + bdL);
        }
      }
      #pragma unroll
      for(int r = 0; r < 16; ++r) rsum += pv[r];
      // pack row pairs to bf16 (truncate): pk[q] = (j=2q lo, j=2q+1 hi) within this lane's rows
      unsigned pk[8];
      #pragma unroll
      for(int q = 0; q < 8; ++q)
        pk[q] = __builtin_amdgcn_perm(fbits(pv[2 * q + 1]), fbits(pv[2 * q]), 0x07060302);
      // exchange with lane^32 to assemble B-frags (k = q5*8+e must hold j = k)
      unsigned sAx = (q5 == 0) ? pk[2] : pk[0];
      unsigned sAy = (q5 == 0) ? pk[3] : pk[1];
      unsigned rAx = (unsigned)__shfl_xor((int)sAx, 32, 64);
      unsigned rAy = (unsigned)__shfl_xor((int)sAy, 32, 64);
      unsigned sBx = (q5 == 0) ? pk[6] : pk[4];
      unsigned sBy = (q5 == 0) ? pk[7] : pk[5];
      unsigned rBx = (unsigned)__shfl_xor((int)sBx, 32, 64);
      unsigned rBy = (unsigned)__shfl_xor((int)sBy, 32, 64);
      union { unsigned u[4]; bf16x8 bf; } f0, f1;
      if(q5 == 0){
        f0.u[0] = pk[0]; f0.u[1] = pk[1]; f0.u[2] = rAx; f0.u[3] = rAy;
        f1.u[0] = pk[4]; f1.u[1] = pk[5]; f1.u[2] = rBx; f1.u[3] = rBy;
      } else {
        f0.u[0] = rAx; f0.u[1] = rAy; f0.u[2] = pk[2]; f0.u[3] = pk[3];
        f1.u[0] = rBx; f1.u[1] = rBy; f1.u[2] = pk[6]; f1.u[3] = pk[7];
      }
      pfrag[jt * 2 + 0] = f0.bf;
      pfrag[jt * 2 + 1] = f1.bf;
    }
    // O^T += V^T · P^T  (2 d-tiles × 4 j k-tiles)
    #pragma unroll
    for(int kt = 0; kt < 4; ++kt){
      bf16x8 va0 = *reinterpret_cast<const bf16x8*>(&vs[p][(m) * ST + kt * 16 + q5 * 8]);
      acc0 = __builtin_amdgcn_mfma_f32_32x32x16_bf16(va0, pfrag[kt], acc0, 0, 0, 0);
      bf16x8 va1 = *reinterpret_cast<const bf16x8*>(&vs[p][(32 + m) * ST + kt * 16 + q5 * 8]);
      acc1 = __builtin_amdgcn_mfma_f32_32x32x16_bf16(va1, pfrag[kt], acc1, 0, 0, 0);
    }
    if(pre){
      const int q2 = p ^ 1;
      *reinterpret_cast<u16x8*>(&ks[q2][jr * ST + c0])     = k0;
      *reinterpret_cast<u16x8*>(&ks[q2][jr * ST + c0 + 8]) = k1;
      *reinterpret_cast<u16x8*>(&vs[q2][jr * ST + c0])     = v0;
      *reinterpret_cast<u16x8*>(&vs[q2][jr * ST + c0 + 8]) = v1;
    }
    __syncthreads();
  }
  // rsum: this lane covered its q5-half rows; lane^32 has the complement (same column i)
  rsum += __shfl_xor(rsum, 32, 64);
  const float rinv = 1.0f / rsum;
  u16* op = av + (size_t)(i_lane * 2 + b) * 1024 + h * 64;
  #pragma unroll
  for(int dt = 0; dt < 2; ++dt){
    const f32x16& A = dt ? acc1 : acc0;
    #pragma unroll
    for(int rq = 0; rq < 4; ++rq){
      ushort4 o;
      o.x = f2bf(A[rq * 4 + 0] * rinv);
      o.y = f2bf(A[rq * 4 + 1] * rinv);
      o.z = f2bf(A[rq * 4 + 2] * rinv);
      o.w = f2bf(A[rq * 4 + 3] * rinv);
      const int d0 = dt * 32 + 8 * rq + 4 * q5;
      *reinterpret_cast<ushort4*>(op + d0) = o;
    }
  }
}

extern "C" void kernel_launch(void* const* d_in, const int* in_sizes, int n_in,
                              void* d_out, int out_size, void* d_ws, size_t ws_size,
                              hipStream_t stream){
  (void)in_sizes; (void)n_in; (void)out_size; (void)ws_size;
  const float* x    = (const float*)d_in[0];
  const float* r    = (const float*)d_in[1];
  const float* rw   = (const float*)d_in[2];
  const float* rr   = (const float*)d_in[3];
  const float* ln_g = (const float*)d_in[4];
  const float* ln_b = (const float*)d_in[5];
  const float* Wqkv = (const float*)d_in[6];
  const float* Wr   = (const float*)d_in[7];
  const float* Wo   = (const float*)d_in[8];
  char* ws = (char*)d_ws;
  u16*   xnb   = (u16*)(ws + 0);                    //  8 MB bf16 [4096,1024]
  u16*   qk    = (u16*)(ws + 8388608);              // 16 MB bf16 [4096,2048] (q | k)
  u16*   av    = (u16*)(ws + 25165824);             //  8 MB bf16 [4096,1024]; doubles as v_nat
  u16*   woT   = (u16*)(ws + 33554432);             //  2 MB bf16 [1024,1024]
  u16*   wqkvT = (u16*)(ws + 35651584);             //  6 MB bf16 [3072,1024]
  u16*   vT    = (u16*)(ws + 41943040);             //  8 MB bf16 [32,64,2048]
  float* rk0   = (float*)(ws + 50331648);           //  4 KB f32 [1024]
  float* cc    = (float*)(ws + 50335744);           // 256 KB f32 [4096,16]
  u16*   vnat  = av;                                // overlay: consumed by vtrans before attn writes av
  float* out   = (float*)d_out;

  transpose_k<<<dim3(96, 32), dim3(32, 8), 0, stream>>>(Wqkv, wqkvT, 1024, 3072);
  transpose_k<<<dim3(32, 32), dim3(32, 8), 0, stream>>>(Wo, woT, 1024, 1024);
  ln_k<<<4096, 256, 0, stream>>>(x, ln_g, ln_b, xnb);
  hipMemsetAsync(rk0, 0, 4096, stream);
  rk0_k<<<dim3(4, 8), 256, 0, stream>>>(r, Wr, rk0);
  gemm_bt_k<2><<<dim3(24, 32), 256, 0, stream>>>(xnb, wqkvT, nullptr, qk, nullptr, vnat, 4096, 3072, 1024);
  vtrans_k<<<dim3(16, 32, 2), 256, 0, stream>>>(vnat, vT);
  c_k<<<1024, 256, 0, stream>>>(qk, rr, rk0, cc);
  attn_k<<<dim3(16, 32), 256, 0, stream>>>(qk, vT, rw, cc, av);
  gemm_bt_k<1><<<dim3(8, 32), 256, 0, stream>>>(av, woT, xnb, nullptr, out, nullptr, 4096, 1024, 1024);
}

// Round 7
// 231.135 us; speedup vs baseline: 1.6464x; 1.0211x over previous
//
#include <hip/hip_runtime.h>

typedef unsigned short u16;
typedef __attribute__((ext_vector_type(8))) __bf16 bf16x8;
typedef __attribute__((ext_vector_type(8))) u16 u16x8;
typedef __attribute__((ext_vector_type(4))) float f32x4;
typedef __attribute__((ext_vector_type(16))) float f32x16;

__device__ __forceinline__ float bf2f(u16 u){
  union { unsigned int i; float f; } v; v.i = ((unsigned int)u) << 16; return v.f;
}
__device__ __forceinline__ u16 f2bf(float f){
  union { float f; unsigned int u; } v; v.f = f;
  unsigned int u = v.u;
  u += 0x7FFFu + ((u >> 16) & 1u);
  return (u16)(u >> 16);
}
__device__ __forceinline__ unsigned fbits(float f){
  union { float f; unsigned u; } v; v.f = f; return v.u;
}
// async global->LDS, 16B per lane; LDS dest = wave-uniform base + lane*16
__device__ __forceinline__ void gld_lds16(const u16* g, u16* l){
  __builtin_amdgcn_global_load_lds((const __attribute__((address_space(1))) unsigned int*)g,
                                   (__attribute__((address_space(3))) unsigned int*)l, 16, 0, 0);
}

// ---------- merged weight transposes f32[R,C] -> bf16[C,R]; block (0,0) also zeroes rk0 ----------
// grid (128, 32): bx<96 -> Wqkv (1024x3072); bx>=96 -> Wo (1024x1024)
__global__ __launch_bounds__(256) void transpose2_k(const float* __restrict__ Wqkv, u16* __restrict__ wqkvT,
                                                    const float* __restrict__ Wo, u16* __restrict__ woT,
                                                    float* __restrict__ rk0z){
  __shared__ float tile[32][33];
  const int tx = threadIdx.x, ty = threadIdx.y;   // block (32,8)
  const float* in; u16* out; int C, bxx;
  if(blockIdx.x < 96){ in = Wqkv; out = wqkvT; C = 3072; bxx = blockIdx.x; }
  else               { in = Wo;   out = woT;   C = 1024; bxx = blockIdx.x - 96; }
  const int R = 1024;
  if(blockIdx.x == 0 && blockIdx.y == 0){
    float4 z = {0.f, 0.f, 0.f, 0.f};
    reinterpret_cast<float4*>(rk0z)[ty * 32 + tx] = z;
  }
  const int bx = bxx * 32, by = blockIdx.y * 32;
  #pragma unroll
  for(int i = 0; i < 32; i += 8)
    tile[ty + i][tx] = in[(size_t)(by + ty + i) * C + bx + tx];
  __syncthreads();
  #pragma unroll
  for(int i = 0; i < 32; i += 8)
    out[(size_t)(bx + ty + i) * R + by + tx] = f2bf(tile[tx][ty + i]);
}

// ---------- LayerNorm rows of 1024: f32 in -> bf16 out ----------
__global__ __launch_bounds__(256) void ln_k(const float* __restrict__ x, const float* __restrict__ gw,
                                            const float* __restrict__ bw, u16* __restrict__ xnb){
  const int row = blockIdx.x, t = threadIdx.x;
  const float* xr = x + (size_t)row * 1024;
  float4 xv = *reinterpret_cast<const float4*>(xr + t * 4);
  float s  = xv.x + xv.y + xv.z + xv.w;
  float s2 = xv.x*xv.x + xv.y*xv.y + xv.z*xv.z + xv.w*xv.w;
  #pragma unroll
  for(int m = 1; m <= 32; m <<= 1){ s += __shfl_xor(s, m, 64); s2 += __shfl_xor(s2, m, 64); }
  __shared__ float red[8];
  const int w = t >> 6, lane = t & 63;
  if(lane == 0){ red[w] = s; red[4 + w] = s2; }
  __syncthreads();
  float S1 = red[0] + red[1] + red[2] + red[3];
  float S2 = red[4] + red[5] + red[6] + red[7];
  float mu = S1 * (1.f/1024.f);
  float var = S2 * (1.f/1024.f) - mu * mu;
  float rstd = rsqrtf(var + 1e-5f);
  float4 gv = *reinterpret_cast<const float4*>(gw + t * 4);
  float4 bv = *reinterpret_cast<const float4*>(bw + t * 4);
  ushort4 o;
  o.x = f2bf((xv.x - mu) * rstd * gv.x + bv.x);
  o.y = f2bf((xv.y - mu) * rstd * gv.y + bv.y);
  o.z = f2bf((xv.z - mu) * rstd * gv.z + bv.z);
  o.w = f2bf((xv.w - mu) * rstd * gv.w + bv.w);
  *reinterpret_cast<ushort4*>(xnb + (size_t)row * 1024 + t * 4) = o;
}

// ---------- rk0 = r @ Wr : [1024], 32-iter chains, atomics (rk0 zeroed by transpose2_k) ----------
__global__ __launch_bounds__(256) void rk0_k(const float* __restrict__ r, const float* __restrict__ Wr,
                                             float* __restrict__ rk0){
  const int n = blockIdx.x * 256 + threadIdx.x;
  const int d0 = blockIdx.y * 32;
  float acc = 0.f;
  for(int d = d0; d < d0 + 32; ++d)
    acc += r[d] * Wr[(size_t)d * 1024 + n];
  atomicAdd(&rk0[n], acc);
}

// ---------- c[ib][h] = sum_d (q + rr) * rk0 ; one wave per ib (4-lane groups = heads) ----------
__global__ __launch_bounds__(256) void c_k(const u16* __restrict__ qk, const float* __restrict__ rr,
                                           const float* __restrict__ rk0, float* __restrict__ cc){
  const int w = threadIdx.x >> 6, lane = threadIdx.x & 63;
  const int ib = blockIdx.x * 4 + w;
  const u16* qp = qk + (size_t)ib * 2048 + lane * 16;
  u16x8 q0 = *reinterpret_cast<const u16x8*>(qp);
  u16x8 q1 = *reinterpret_cast<const u16x8*>(qp + 8);
  const float* rrp = rr + lane * 16;
  const float* rkp = rk0 + lane * 16;
  float s = 0.f;
  #pragma unroll
  for(int e = 0; e < 8; ++e){
    s += (bf2f(q0[e]) + rrp[e]) * rkp[e];
    s += (bf2f(q1[e]) + rrp[8 + e]) * rkp[8 + e];
  }
  s += __shfl_xor(s, 1, 64);
  s += __shfl_xor(s, 2, 64);
  if((lane & 3) == 0) cc[(size_t)ib * 16 + (lane >> 2)] = s;
}

// ---------- V transpose: v_nat[i*2+b][h*64+d] -> vT[(b*16+h)*64+d][i] ----------
__global__ __launch_bounds__(256) void vtrans_k(const u16* __restrict__ vnat, u16* __restrict__ vT){
  __shared__ u16 tl[128][40];
  const int t = threadIdx.x;
  const int i0 = blockIdx.x * 128, c0 = blockIdx.y * 32, b = blockIdx.z;
  {
    const int ii = t & 127, cs = (t >> 7) * 16;
    const u16* p = vnat + (size_t)((i0 + ii) * 2 + b) * 1024 + c0 + cs;
    *reinterpret_cast<u16x8*>(&tl[ii][cs])     = *reinterpret_cast<const u16x8*>(p);
    *reinterpret_cast<u16x8*>(&tl[ii][cs + 8]) = *reinterpret_cast<const u16x8*>(p + 8);
  }
  __syncthreads();
  const int dr = t & 31, seg = t >> 5;          // seg 0..7
  const int R = (b * 16 + (c0 >> 6)) * 64 + (c0 & 63) + dr;
  u16 tmp[16];
  #pragma unroll
  for(int e = 0; e < 16; ++e) tmp[e] = tl[seg * 16 + e][dr];
  u16* op = vT + (size_t)R * 2048 + i0 + seg * 16;
  *reinterpret_cast<u16x8*>(op)     = *reinterpret_cast<u16x8*>(&tmp[0]);
  *reinterpret_cast<u16x8*>(op + 8) = *reinterpret_cast<u16x8*>(&tmp[8]);
}

// ---------- GEMM1 qkv: [4096,3072] = xnb[4096,1024] @ wqkvT[3072,1024]^T ----------
// BK=64 via two unpadded 32-k subtiles (half the barrier drains, gld-safe layout);
// block-uniform epilogue: bx<16 -> qk (stride 2048), else -> coalesced vnat
__global__ __launch_bounds__(256) void gemm_qkv_k(const u16* __restrict__ A, const u16* __restrict__ BT,
                                                  u16* __restrict__ Cb, u16* __restrict__ vnat){
  __shared__ u16 sA[2][128 * 32];
  __shared__ u16 sB[2][128 * 32];
  const int t = threadIdx.x;
  const int row0 = blockIdx.y * 128, col0 = blockIdx.x * 128;
  const int w = t >> 6, lane = t & 63, g = lane >> 4, lq = lane & 15;
  const int wr = (w >> 1) * 64, wc = (w & 1) * 64;
  const int K = 1024;
  f32x4 zero4 = {0.f, 0.f, 0.f, 0.f};
  f32x4 acc[4][4];
  #pragma unroll
  for(int mi = 0; mi < 4; ++mi)
    #pragma unroll
    for(int ni = 0; ni < 4; ++ni) acc[mi][ni] = zero4;

  for(int kt = 0; kt < K; kt += 64){
    #pragma unroll
    for(int ks = 0; ks < 2; ++ks){
      const int kk = kt + ks * 32;
      gld_lds16(A  + (size_t)(row0 +      (t >> 2)) * K + kk + (t & 3) * 8, &sA[ks][w * 512]);
      gld_lds16(A  + (size_t)(row0 + 64 + (t >> 2)) * K + kk + (t & 3) * 8, &sA[ks][2048 + w * 512]);
      gld_lds16(BT + (size_t)(col0 +      (t >> 2)) * K + kk + (t & 3) * 8, &sB[ks][w * 512]);
      gld_lds16(BT + (size_t)(col0 + 64 + (t >> 2)) * K + kk + (t & 3) * 8, &sB[ks][2048 + w * 512]);
    }
    __syncthreads();
    #pragma unroll
    for(int ks = 0; ks < 2; ++ks){
      bf16x8 af[4];
      #pragma unroll
      for(int mi = 0; mi < 4; ++mi)
        af[mi] = *reinterpret_cast<const bf16x8*>(&sA[ks][(wr + mi * 16 + lq) * 32 + g * 8]);
      #pragma unroll
      for(int ni = 0; ni < 4; ++ni){
        bf16x8 bfr = *reinterpret_cast<const bf16x8*>(&sB[ks][(wc + ni * 16 + lq) * 32 + g * 8]);
        #pragma unroll
        for(int mi = 0; mi < 4; ++mi)
          acc[mi][ni] = __builtin_amdgcn_mfma_f32_16x16x32_bf16(af[mi], bfr, acc[mi][ni], 0, 0, 0);
      }
    }
    __syncthreads();
  }
  if(blockIdx.x < 16){
    #pragma unroll
    for(int mi = 0; mi < 4; ++mi)
      #pragma unroll
      for(int ni = 0; ni < 4; ++ni)
        #pragma unroll
        for(int rg = 0; rg < 4; ++rg){
          const int row = row0 + wr + mi * 16 + g * 4 + rg;
          const int col = col0 + wc + ni * 16 + lq;
          Cb[(size_t)row * 2048 + col] = f2bf(acc[mi][ni][rg]);
        }
  } else {
    #pragma unroll
    for(int mi = 0; mi < 4; ++mi)
      #pragma unroll
      for(int ni = 0; ni < 4; ++ni)
        #pragma unroll
        for(int rg = 0; rg < 4; ++rg){
          const int row = row0 + wr + mi * 16 + g * 4 + rg;
          const int col = col0 + wc + ni * 16 + lq - 2048;
          vnat[(size_t)row * 1024 + col] = f2bf(acc[mi][ni][rg]);
        }
  }
}

// ---------- GEMM2 out: f32[4096,1024] = av @ woT^T + residual(xnb) ----------
// 128(M)x64(N) tiles -> grid (16,32)=512 blocks = 2 blocks/CU (was 1)
__global__ __launch_bounds__(256) void gemm_out_k(const u16* __restrict__ A, const u16* __restrict__ BT,
                                                  const u16* __restrict__ res, float* __restrict__ Cf){
  __shared__ u16 sA[128 * 32];
  __shared__ u16 sB[64 * 32];
  const int t = threadIdx.x;
  const int row0 = blockIdx.y * 128, col0 = blockIdx.x * 64;
  const int w = t >> 6, lane = t & 63, g = lane >> 4, lq = lane & 15;
  const int wr = (w >> 1) * 64, wc = (w & 1) * 32;
  const int K = 1024, N = 1024;
  f32x4 zero4 = {0.f, 0.f, 0.f, 0.f};
  f32x4 acc[4][2];
  #pragma unroll
  for(int mi = 0; mi < 4; ++mi)
    #pragma unroll
    for(int ni = 0; ni < 2; ++ni) acc[mi][ni] = zero4;

  for(int kt = 0; kt < K; kt += 32){
    gld_lds16(A  + (size_t)(row0 +      (t >> 2)) * K + kt + (t & 3) * 8, &sA[w * 512]);
    gld_lds16(A  + (size_t)(row0 + 64 + (t >> 2)) * K + kt + (t & 3) * 8, &sA[2048 + w * 512]);
    gld_lds16(BT + (size_t)(col0 +      (t >> 2)) * K + kt + (t & 3) * 8, &sB[w * 512]);
    __syncthreads();
    bf16x8 af[4];
    #pragma unroll
    for(int mi = 0; mi < 4; ++mi)
      af[mi] = *reinterpret_cast<const bf16x8*>(&sA[(wr + mi * 16 + lq) * 32 + g * 8]);
    #pragma unroll
    for(int ni = 0; ni < 2; ++ni){
      bf16x8 bfr = *reinterpret_cast<const bf16x8*>(&sB[(wc + ni * 16 + lq) * 32 + g * 8]);
      #pragma unroll
      for(int mi = 0; mi < 4; ++mi)
        acc[mi][ni] = __builtin_amdgcn_mfma_f32_16x16x32_bf16(af[mi], bfr, acc[mi][ni], 0, 0, 0);
    }
    __syncthreads();
  }
  #pragma unroll
  for(int mi = 0; mi < 4; ++mi)
    #pragma unroll
    for(int ni = 0; ni < 2; ++ni)
      #pragma unroll
      for(int rg = 0; rg < 4; ++rg){
        const int row = row0 + wr + mi * 16 + g * 4 + rg;
        const int col = col0 + wc + ni * 16 + lq;
        Cf[(size_t)row * N + col] = acc[mi][ni][rg] + bf2f(res[(size_t)row * N + col]);
      }
}

// ---------- flash attention: 32x32x16 MFMA, S^T form, shfl-exchange P (no ps LDS) ----------
// grid: (S/128, B*H); block 256 = 4 waves; wave w owns 32 q-rows [i0+32w, i0+32w+32)
// S^T C-layout: col i = lane&31, row j = (r&3)+8*(r>>2)+4*(lane>>5)
// PV B-operand: n = lane&31, k = (lane>>5)*8+e  -> one lane^32 exchange per 16-j k-tile
__global__ __launch_bounds__(256) void attn_k(const u16* __restrict__ qk, const u16* __restrict__ vT,
                                              const float* __restrict__ rw, const float* __restrict__ cc,
                                              u16* __restrict__ av){
  constexpr int S = 2048, ST = 74;  // 37 dwords row stride: bank = (5m+4q5)%32, 2-way free
  __shared__ u16 ks[2][64 * ST];    // K tile: rows=key j, cols=d
  __shared__ u16 vs[2][64 * ST];    // V^T tile: rows=d, cols=key j
  const int t = threadIdx.x;
  const int i0 = blockIdx.x * 128;
  const int bh = blockIdx.y;                    // b*16 + h
  const int b = bh >> 4, h = bh & 15;
  const int w = t >> 6, lane = t & 63, m = lane & 31, q5 = lane >> 5;
  const int iw0 = i0 + w * 32;
  const int i_lane = iw0 + m;
  const float SC = 0.125f * 1.4426950408889634f;   // scale * log2(e): exp(x)=exp2(SC-domain)

  // Q B-frags (loop-invariant): lane holds Q[i=m][d=kt*16+q5*8+e], pre-scaled by SC
  bf16x8 qf[4];
  {
    const u16* qp = qk + (size_t)(i_lane * 2 + b) * 2048 + h * 64;
    const float* rwp = rw + h * 64;
    #pragma unroll
    for(int kt = 0; kt < 4; ++kt){
      const int dbase = kt * 16 + q5 * 8;
      u16x8 qv = *reinterpret_cast<const u16x8*>(qp + dbase);
      u16x8 a;
      #pragma unroll
      for(int e = 0; e < 8; ++e) a[e] = f2bf((bf2f(qv[e]) + rwp[dbase + e]) * SC);
      qf[kt] = *reinterpret_cast<bf16x8*>(&a);
    }
  }
  const float ciL = cc[(size_t)(i_lane * 2 + b) * 16 + h] * SC;
  const float cpL = (i_lane + 1 < S) ? cc[(size_t)((i_lane + 1) * 2 + b) * 16 + h] * SC : 0.0f;

  f32x16 acc0, acc1, z16;
  #pragma unroll
  for(int e = 0; e < 16; ++e) z16[e] = 0.f;
  acc0 = z16; acc1 = z16;
  float rsum = 0.f;

  const int jr = t >> 2, c0 = (t & 3) * 16;     // staging: row, u16 col offset
  {
    const u16* kp = qk + (size_t)(jr * 2 + b) * 2048 + 1024 + h * 64 + c0;
    *reinterpret_cast<u16x8*>(&ks[0][jr * ST + c0])     = *reinterpret_cast<const u16x8*>(kp);
    *reinterpret_cast<u16x8*>(&ks[0][jr * ST + c0 + 8]) = *reinterpret_cast<const u16x8*>(kp + 8);
    const u16* vp = vT + ((size_t)bh * 64 + jr) * 2048 + c0;
    *reinterpret_cast<u16x8*>(&vs[0][jr * ST + c0])     = *reinterpret_cast<const u16x8*>(vp);
    *reinterpret_cast<u16x8*>(&vs[0][jr * ST + c0 + 8]) = *reinterpret_cast<const u16x8*>(vp + 8);
  }
  __syncthreads();

  for(int n = 0; n < 32; ++n){
    const int p = n & 1;
    u16x8 k0, k1, v0, v1;
    const bool pre = (n + 1 < 32);
    if(pre){
      const int j0n = (n + 1) * 64;
      const u16* kp = qk + (size_t)((j0n + jr) * 2 + b) * 2048 + 1024 + h * 64 + c0;
      k0 = *reinterpret_cast<const u16x8*>(kp);
      k1 = *reinterpret_cast<const u16x8*>(kp + 8);
      const u16* vp = vT + ((size_t)bh * 64 + jr) * 2048 + j0n + c0;
      v0 = *reinterpret_cast<const u16x8*>(vp);
      v1 = *reinterpret_cast<const u16x8*>(vp + 8);
    }
    const int j0 = n * 64;
    bf16x8 pfrag[4];                            // PV B-frags for the 4 16-j k-tiles
    #pragma unroll
    for(int jt = 0; jt < 2; ++jt){
      const int tj0 = j0 + jt * 32;
      f32x16 s = z16;
      #pragma unroll
      for(int kt = 0; kt < 4; ++kt){
        bf16x8 ka = *reinterpret_cast<const bf16x8*>(&ks[p][(jt * 32 + m) * ST + kt * 16 + q5 * 8]);
        s = __builtin_amdgcn_mfma_f32_32x32x16_bf16(ka, qf[kt], s, 0, 0, 0);
      }
      // exp2(s + bd) ; bd = ciL (j<=i), 0 (j==i+1), cpL (j>=i+2)
      float pv[16];
      if(tj0 + 31 <= iw0){                      // whole tile below diagonal for all lanes
        #pragma unroll
        for(int r = 0; r < 16; ++r) pv[r] = __builtin_amdgcn_exp2f(s[r] + ciL);
      } else if(tj0 >= iw0 + 33){               // whole tile above
        #pragma unroll
        for(int r = 0; r < 16; ++r) pv[r] = __builtin_amdgcn_exp2f(s[r] + cpL);
      } else {
        #pragma unroll
        for(int r = 0; r < 16; ++r){
          const int j = tj0 + (r & 3) + 8 * (r >> 2) + 4 * q5;
          const float t1 = (j <= i_lane) ? ciL : cpL;
          const float bdL = (j == i_lane + 1) ? 0.0f : t1;
          pv[r] = __builtin_amdgcn_exp2f(s[r] + bdL);
        }
      }
      #pragma unroll
      for(int r = 0; r < 16; ++r) rsum += pv[r];
      // pack row pairs to bf16 (truncate): pk[q] = (j=2q lo, j=2q+1 hi) within this lane's rows
      unsigned pk[8];
      #pragma unroll
      for(int q = 0; q < 8; ++q)
        pk[q] = __builtin_amdgcn_perm(fbits(pv[2 * q + 1]), fbits(pv[2 * q]), 0x07060302);
      // exchange with lane^32 to assemble B-frags (k = q5*8+e must hold j = k)
      unsigned sAx = (q5 == 0) ? pk[2] : pk[0];
      unsigned sAy = (q5 == 0) ? pk[3] : pk[1];
      unsigned rAx = (unsigned)__shfl_xor((int)sAx, 32, 64);
      unsigned rAy = (unsigned)__shfl_xor((int)sAy, 32, 64);
      unsigned sBx = (q5 == 0) ? pk[6] : pk[4];
      unsigned sBy = (q5 == 0) ? pk[7] : pk[5];
      unsigned rBx = (unsigned)__shfl_xor((int)sBx, 32, 64);
      unsigned rBy = (unsigned)__shfl_xor((int)sBy, 32, 64);
      union { unsigned u[4]; bf16x8 bf; } f0, f1;
      if(q5 == 0){
        f0.u[0] = pk[0]; f0.u[1] = pk[1]; f0.u[2] = rAx; f0.u[3] = rAy;
        f1.u[0] = pk[4]; f1.u[1] = pk[5]; f1.u[2] = rBx; f1.u[3] = rBy;
      } else {
        f0.u[0] = rAx; f0.u[1] = rAy; f0.u[2] = pk[2]; f0.u[3] = pk[3];
        f1.u[0] = rBx; f1.u[1] = rBy; f1.u[2] = pk[6]; f1.u[3] = pk[7];
      }
      pfrag[jt * 2 + 0] = f0.bf;
      pfrag[jt * 2 + 1] = f1.bf;
    }
    // O^T += V^T · P^T  (2 d-tiles × 4 j k-tiles)
    #pragma unroll
    for(int kt = 0; kt < 4; ++kt){
      bf16x8 va0 = *reinterpret_cast<const bf16x8*>(&vs[p][(m) * ST + kt * 16 + q5 * 8]);
      acc0 = __builtin_amdgcn_mfma_f32_32x32x16_bf16(va0, pfrag[kt], acc0, 0, 0, 0);
      bf16x8 va1 = *reinterpret_cast<const bf16x8*>(&vs[p][(32 + m) * ST + kt * 16 + q5 * 8]);
      acc1 = __builtin_amdgcn_mfma_f32_32x32x16_bf16(va1, pfrag[kt], acc1, 0, 0, 0);
    }
    if(pre){
      const int q2 = p ^ 1;
      *reinterpret_cast<u16x8*>(&ks[q2][jr * ST + c0])     = k0;
      *reinterpret_cast<u16x8*>(&ks[q2][jr * ST + c0 + 8]) = k1;
      *reinterpret_cast<u16x8*>(&vs[q2][jr * ST + c0])     = v0;
      *reinterpret_cast<u16x8*>(&vs[q2][jr * ST + c0 + 8]) = v1;
    }
    __syncthreads();
  }
  // rsum: this lane covered its q5-half rows; lane^32 has the complement (same column i)
  rsum += __shfl_xor(rsum, 32, 64);
  const float rinv = 1.0f / rsum;
  u16* op = av + (size_t)(i_lane * 2 + b) * 1024 + h * 64;
  #pragma unroll
  for(int dt = 0; dt < 2; ++dt){
    const f32x16& A = dt ? acc1 : acc0;
    #pragma unroll
    for(int rq = 0; rq < 4; ++rq){
      ushort4 o;
      o.x = f2bf(A[rq * 4 + 0] * rinv);
      o.y = f2bf(A[rq * 4 + 1] * rinv);
      o.z = f2bf(A[rq * 4 + 2] * rinv);
      o.w = f2bf(A[rq * 4 + 3] * rinv);
      const int d0 = dt * 32 + 8 * rq + 4 * q5;
      *reinterpret_cast<ushort4*>(op + d0) = o;
    }
  }
}

extern "C" void kernel_launch(void* const* d_in, const int* in_sizes, int n_in,
                              void* d_out, int out_size, void* d_ws, size_t ws_size,
                              hipStream_t stream){
  (void)in_sizes; (void)n_in; (void)out_size; (void)ws_size;
  const float* x    = (const float*)d_in[0];
  const float* r    = (const float*)d_in[1];
  const float* rw   = (const float*)d_in[2];
  const float* rr   = (const float*)d_in[3];
  const float* ln_g = (const float*)d_in[4];
  const float* ln_b = (const float*)d_in[5];
  const float* Wqkv = (const float*)d_in[6];
  const float* Wr   = (const float*)d_in[7];
  const float* Wo   = (const float*)d_in[8];
  char* ws = (char*)d_ws;
  u16*   xnb   = (u16*)(ws + 0);                    //  8 MB bf16 [4096,1024]
  u16*   qk    = (u16*)(ws + 8388608);              // 16 MB bf16 [4096,2048] (q | k)
  u16*   av    = (u16*)(ws + 25165824);             //  8 MB bf16 [4096,1024]; doubles as v_nat
  u16*   woT   = (u16*)(ws + 33554432);             //  2 MB bf16 [1024,1024]
  u16*   wqkvT = (u16*)(ws + 35651584);             //  6 MB bf16 [3072,1024]
  u16*   vT    = (u16*)(ws + 41943040);             //  8 MB bf16 [32,64,2048]
  float* rk0   = (float*)(ws + 50331648);           //  4 KB f32 [1024]
  float* cc    = (float*)(ws + 50335744);           // 256 KB f32 [4096,16]
  u16*   vnat  = av;                                // overlay: consumed by vtrans before attn writes av
  float* out   = (float*)d_out;

  transpose2_k<<<dim3(128, 32), dim3(32, 8), 0, stream>>>(Wqkv, wqkvT, Wo, woT, rk0);
  ln_k<<<4096, 256, 0, stream>>>(x, ln_g, ln_b, xnb);
  rk0_k<<<dim3(4, 32), 256, 0, stream>>>(r, Wr, rk0);
  gemm_qkv_k<<<dim3(24, 32), 256, 0, stream>>>(xnb, wqkvT, qk, vnat);
  vtrans_k<<<dim3(16, 32, 2), 256, 0, stream>>>(vnat, vT);
  c_k<<<1024, 256, 0, stream>>>(qk, rr, rk0, cc);
  attn_k<<<dim3(16, 32), 256, 0, stream>>>(qk, vT, rw, cc, av);
  gemm_out_k<<<dim3(16, 32), 256, 0, stream>>>(av, woT, xnb, out);
}